// Round 15
// baseline (437.404 us; speedup 1.0000x reference)
//
#include <hip/hip_runtime.h>

#define BB  8
#define NP  2048
#define KNB 20
#define KP  10      // reduced ripple depth (validity-checked, exact fallback)
#define SS  40960   // spatial per batch, layers 1-4

typedef unsigned short bf16_t;
typedef __attribute__((ext_vector_type(8))) short short8_t;   // MFMA A/B frag (8 bf16)
typedef __attribute__((ext_vector_type(4))) float f32x4;      // MFMA C/D frag

static __device__ __forceinline__ float bf2f(unsigned short u) {
    return __uint_as_float(((unsigned)u) << 16);
}
static __device__ __forceinline__ bf16_t f2bf(float f) {
    unsigned u = __float_as_uint(f);
    return (bf16_t)((u + 0x7fffu + ((u >> 16) & 1u)) >> 16);   // RNE
}

#if __has_builtin(__builtin_amdgcn_fmed3f)
#define MED3(a, b, c) __builtin_amdgcn_fmed3f((a), (b), (c))
#else
#define MED3(a, b, c) fmaxf(fminf((a), (b)), fminf(fmaxf((a), (b)), (c)))
#endif

// ==== kNN v4 (KP=10, R9-verified) ====
static __device__ __forceinline__ float negdist(float4 me, float4 p) {
    float d = me.x * p.x + me.y * p.y + me.z * p.z;
    return 2.0f * d - me.w - p.w;
}

#define BDECL(t) float bv##t = -3.4e38f;
#define MCH(t, p) bv##t = MED3(v, bv##p, bv##t);
#define BSHIFT(t, n) bv##t = bv##n;
#define FDECL(t) float fv##t = -3.4e38f;
#define FMCH(t, p) fv##t = MED3(v, fv##p, fv##t);
#define FSHIFT(t, n) fv##t = fv##n;

__global__ __launch_bounds__(256) void knn_kernel(const float* __restrict__ x,
                                                  int* __restrict__ idx) {
    __shared__ float4 tile[2064];      // 2048 + (j>>7) swizzle pad, 33 KB
    __shared__ int   cnt[16];
    __shared__ float svv[16][44];
    __shared__ int   svj[16][44];
    const int tid  = threadIdx.x;
    const int b    = blockIdx.x >> 7;
    const int pblk = blockIdx.x & 127;
    const int pl   = tid >> 4;         // local point 0..15
    const int seg  = tid & 15;         // segment 0..15 (128 cands each)
    const int i    = pblk * 16 + pl;
    const float* xb = x + (size_t)b * 3 * NP;

    for (int j = tid; j < NP; j += 256) {
        float a0 = xb[j], a1 = xb[NP + j], a2 = xb[2 * NP + j];
        tile[j + (j >> 7)] = make_float4(a0, a1, a2, a0 * a0 + a1 * a1 + a2 * a2);
    }
    if (tid < 16) cnt[tid] = 0;
    __syncthreads();
    const float4 me = tile[i + (i >> 7)];
    const float4* tseg = &tile[seg * 129];

    // ---- phase 1: per-lane top-KP VALUES, depth-10 med3 ripple ----
    BDECL(0) BDECL(1) BDECL(2) BDECL(3) BDECL(4)
    BDECL(5) BDECL(6) BDECL(7) BDECL(8) BDECL(9)
    for (int t = 0; t < 128; ++t) {
        float v = negdist(me, tseg[t]);
        MCH(9,8) MCH(8,7) MCH(7,6) MCH(6,5) MCH(5,4)
        MCH(4,3) MCH(3,2) MCH(2,1) MCH(1,0)
        bv0 = fmaxf(bv0, v);
    }

    // ---- theta: 20 rounds of 16-lane argmax-with-pop (values only) ----
    float theta = -3.4e38f;
    int pops = 0;
    for (int r = 0; r < KNB; ++r) {
        float mv = bv0; int ms = seg;
#pragma unroll
        for (int s = 1; s <= 8; s <<= 1) {
            float ov = __shfl_xor(mv, s, 64);
            int   os = __shfl_xor(ms, s, 64);
            if (ov > mv || (ov == mv && os < ms)) { mv = ov; ms = os; }
        }
        if (seg == ms) {   // exactly one lane of the 16-group pops its head
            BSHIFT(0,1) BSHIFT(1,2) BSHIFT(2,3) BSHIFT(3,4) BSHIFT(4,5)
            BSHIFT(5,6) BSHIFT(6,7) BSHIFT(7,8) BSHIFT(8,9)
            bv9 = -3.4e38f;
            ++pops;
        }
        theta = mv;        // after round 19: the 20th-largest value
    }

    // ---- validity: a fully-drained lane may have corrupted later pops ----
    int bad = (pops >= KP) ? 1 : 0;
#pragma unroll
    for (int s = 1; s <= 8; s <<= 1) bad |= __shfl_xor(bad, s, 64);
    if (bad) {             // rare (~3e-6/point): exact full-depth redo
        FDECL(0)  FDECL(1)  FDECL(2)  FDECL(3)  FDECL(4)
        FDECL(5)  FDECL(6)  FDECL(7)  FDECL(8)  FDECL(9)
        FDECL(10) FDECL(11) FDECL(12) FDECL(13) FDECL(14)
        FDECL(15) FDECL(16) FDECL(17) FDECL(18) FDECL(19)
        for (int t = 0; t < 128; ++t) {
            float v = negdist(me, tseg[t]);
            FMCH(19,18) FMCH(18,17) FMCH(17,16) FMCH(16,15) FMCH(15,14)
            FMCH(14,13) FMCH(13,12) FMCH(12,11) FMCH(11,10) FMCH(10,9)
            FMCH(9,8)   FMCH(8,7)   FMCH(7,6)   FMCH(6,5)   FMCH(5,4)
            FMCH(4,3)   FMCH(3,2)   FMCH(2,1)   FMCH(1,0)
            fv0 = fmaxf(fv0, v);
        }
        theta = -3.4e38f;
        for (int r = 0; r < KNB; ++r) {
            float mv = fv0; int ms = seg;
#pragma unroll
            for (int s = 1; s <= 8; s <<= 1) {
                float ov = __shfl_xor(mv, s, 64);
                int   os = __shfl_xor(ms, s, 64);
                if (ov > mv || (ov == mv && os < ms)) { mv = ov; ms = os; }
            }
            if (seg == ms) {
                FSHIFT(0,1)   FSHIFT(1,2)   FSHIFT(2,3)   FSHIFT(3,4)   FSHIFT(4,5)
                FSHIFT(5,6)   FSHIFT(6,7)   FSHIFT(7,8)   FSHIFT(8,9)   FSHIFT(9,10)
                FSHIFT(10,11) FSHIFT(11,12) FSHIFT(12,13) FSHIFT(13,14) FSHIFT(14,15)
                FSHIFT(15,16) FSHIFT(16,17) FSHIFT(17,18) FSHIFT(18,19)
                fv19 = -3.4e38f;
            }
            theta = mv;
        }
    }

    // ---- phase 2: collect survivors (v >= theta), identical arithmetic ----
    for (int t = 0; t < 128; ++t) {
        float v = negdist(me, tseg[t]);
        if (v >= theta) {
            int k = atomicAdd(&cnt[pl], 1);
            if (k < 44) { svv[pl][k] = v; svj[pl][k] = seg * 128 + t; }
        }
    }
    __syncthreads();

    // ---- emit: rank = #{(v',j') : v'>v or (v'==v && j'<j)} ----
    int n = cnt[pl]; if (n > 44) n = 44;
    int* o = idx + ((size_t)b * NP + i) * KNB;
    for (int e = seg; e < n; e += 16) {
        float v = svv[pl][e]; int j = svj[pl][e];
        int rank = 0;
        for (int q = 0; q < n; ++q) {
            float vq = svv[pl][q]; int jq = svj[pl][q];
            rank += (vq > v || (vq == v && jq < j)) ? 1 : 0;
        }
        if (rank < KNB) o[rank] = j;
    }
}

// ==== graph feature, channel-contiguous f[b][s][32]; ch 0-5 real, 6-31 ZERO ====
__global__ void gather_kernel(const float* __restrict__ x, const int* __restrict__ idx,
                              bf16_t* __restrict__ f) {
    int s = blockIdx.x * 256 + threadIdx.x;
    int b = blockIdx.y;
    int n = s / KNB;
    int j = idx[(size_t)b * SS + s];
    const float* xb = x + (size_t)b * 3 * NP;
    ushort4 u0, u1;
    u0.x = f2bf(xb[j]);          u0.y = f2bf(xb[NP + j]);
    u0.z = f2bf(xb[2 * NP + j]); u0.w = f2bf(xb[n]);
    u1.x = f2bf(xb[NP + n]);     u1.y = f2bf(xb[2 * NP + n]);
    u1.z = 0; u1.w = 0;
    ushort4 z4; z4.x = 0; z4.y = 0; z4.z = 0; z4.w = 0;
    bf16_t* fb = f + ((size_t)b * SS + s) * 32;
    *(ushort4*)(fb)      = u0;
    *(ushort4*)(fb + 4)  = u1;
    *(ushort4*)(fb + 8)  = z4;
    *(ushort4*)(fb + 12) = z4;
    *(ushort4*)(fb + 16) = z4;
    *(ushort4*)(fb + 20) = z4;
    *(ushort4*)(fb + 24) = z4;
    *(ushort4*)(fb + 28) = z4;
}

// ==== weights fp32 -> bf16, zero-padded rows ====
__global__ void wconv_kernel(const float* __restrict__ src, bf16_t* __restrict__ dst,
                             int O, int CI, int CIP) {
    int t = blockIdx.x * 256 + threadIdx.x;
    if (t >= O * CIP) return;
    int o = t / CIP, cp = t - o * CIP;
    dst[t] = (cp < CI) ? f2bf(src[o * CI + cp]) : (bf16_t)0;
}

// ==== zero the layer-stats accumulators (2048 floats) ====
__global__ void zstats_kernel(float* __restrict__ p) {
    p[blockIdx.x * 256 + threadIdx.x] = 0.f;
}

// ==== elementwise BN+ReLU in place on bf16 activations [.., C contiguous] ====
__global__ void bnrelu_kernel(bf16_t* __restrict__ y, const float* __restrict__ ab,
                              int C) {
    size_t e0 = ((size_t)blockIdx.x * 256 + threadIdx.x) * 8;
    int c0 = (int)(e0 & (size_t)(C - 1));
    uint4 r = *(uint4*)(y + e0);
    float4 a0 = *(const float4*)(ab + c0);
    float4 a1 = *(const float4*)(ab + c0 + 4);
    float4 d0 = *(const float4*)(ab + C + c0);
    float4 d1 = *(const float4*)(ab + C + c0 + 4);
    float v0 = bf2f((unsigned short)(r.x & 0xffffu)), v1 = bf2f((unsigned short)(r.x >> 16));
    float v2 = bf2f((unsigned short)(r.y & 0xffffu)), v3 = bf2f((unsigned short)(r.y >> 16));
    float v4 = bf2f((unsigned short)(r.z & 0xffffu)), v5 = bf2f((unsigned short)(r.z >> 16));
    float v6 = bf2f((unsigned short)(r.w & 0xffffu)), v7 = bf2f((unsigned short)(r.w >> 16));
    v0 = fmaxf(fmaf(a0.x, v0, d0.x), 0.f); v1 = fmaxf(fmaf(a0.y, v1, d0.y), 0.f);
    v2 = fmaxf(fmaf(a0.z, v2, d0.z), 0.f); v3 = fmaxf(fmaf(a0.w, v3, d0.w), 0.f);
    v4 = fmaxf(fmaf(a1.x, v4, d1.x), 0.f); v5 = fmaxf(fmaf(a1.y, v5, d1.y), 0.f);
    v6 = fmaxf(fmaf(a1.z, v6, d1.z), 0.f); v7 = fmaxf(fmaf(a1.w, v7, d1.w), 0.f);
    r.x = (unsigned)f2bf(v0) | ((unsigned)f2bf(v1) << 16);
    r.y = (unsigned)f2bf(v2) | ((unsigned)f2bf(v3) << 16);
    r.z = (unsigned)f2bf(v4) | ((unsigned)f2bf(v5) << 16);
    r.w = (unsigned)f2bf(v6) | ((unsigned)f2bf(v7) << 16);
    *(uint4*)(y + e0) = r;
}

// ==== MFMA conv: R15 = R14 + channel-group folding (G template param).
// G=2 for L3/L4: each block keeps TWO 64-channel A-fragment sets resident
// (iteration-invariant) and runs the MFMA chain twice per B-tile -> B loads
// per row halved, MFMA density per iteration doubled, fixed per-iteration
// stall (R8/R12-fitted ~4k cyc) amortized 2x. Per-group TILE1+barrier+pool
// phase; ytile ping-pongs per PHASE (it*G+g); WAR safe since each wave
// lgkm-drains its pool reads before signalling the next barrier.
#define MF(A, B, C) C = __builtin_amdgcn_mfma_f32_16x16x32_bf16(A, B, C, 0, 0, 0);

#define LGKM_BARRIER() { \
    asm volatile("s_waitcnt lgkmcnt(0)" ::: "memory"); \
    __builtin_amdgcn_s_barrier(); \
    asm volatile("" ::: "memory"); }

#define TILE1(CC, CT, STt, YT) { \
    ushort4 t4; \
    t4.x = f2bf(CC[0]); t4.y = f2bf(CC[1]); \
    t4.z = f2bf(CC[2]); t4.w = f2bf(CC[3]); \
    *(ushort4*)&YT[w * 32 + (STt) * 16 + col][(CT) * 16 + quad * 4] = t4; }

// shared epilogue body; expects c00..c31 in scope. PH = global phase
// (buffer select), GI = channel-group index within block.
#define EPILOGUE(PH, GI) { \
    bf16_t (*yt)[68] = ytile[(PH) & (NBUF - 1)]; \
    const int cobg = cob + (GI) * 64; \
    TILE1(c00,0,0,yt) TILE1(c10,1,0,yt) TILE1(c20,2,0,yt) TILE1(c30,3,0,yt) \
    TILE1(c01,0,1,yt) TILE1(c11,1,1,yt) TILE1(c21,2,1,yt) TILE1(c31,3,1,yt) \
    LGKM_BARRIER() \
    if constexpr (ST) { \
        const int row0 = blockIdx.x * (SR * NS) + (ITV_OF(PH)) * SR; \
        for (int i = tid; i < SR * 16; i += NW * 64) { \
            int row = i >> 4, c4 = (i & 15) * 4; \
            ushort4 yv = *(const ushort4*)&yt[row][c4]; \
            *(ushort4*)(Yout + ((size_t)b * SROWS + row0 + row) * COUT_T + cobg + c4) = yv; \
            if constexpr (!POOL) { \
                float v0 = bf2f(yv.x), v1 = bf2f(yv.y); \
                float v2 = bf2f(yv.z), v3 = bf2f(yv.w); \
                sv0 += v0; qv0 = fmaf(v0, v0, qv0); \
                sv1 += v1; qv1 = fmaf(v1, v1, qv1); \
                sv2 += v2; qv2 = fmaf(v2, v2, qv2); \
                sv3 += v3; qv3 = fmaf(v3, v3, qv3); \
            } \
        } \
    } \
    if constexpr (POOL) { \
        const int nbase = (blockIdx.x * NS + (ITV_OF(PH))) * 8; \
        for (int i = tid; i < 8 * 32; i += NW * 64) { \
            const int nl = i >> 5, c2 = (i & 31) * 2; \
            float m0 = -3.4e38f, m1 = -3.4e38f; \
            _Pragma("unroll") \
            for (int k = 0; k < KNB; ++k) { \
                unsigned u = *(const unsigned*)&yt[nl * 20 + k][c2]; \
                float v0 = bf2f((unsigned short)(u & 0xffffu)); \
                float v1 = bf2f((unsigned short)(u >> 16)); \
                m0 = fmaxf(m0, v0); m1 = fmaxf(m1, v1); \
                svA[GI] += v0; qvA[GI] = fmaf(v0, v0, qvA[GI]); \
                svB[GI] += v1; qvB[GI] = fmaf(v1, v1, qvB[GI]); \
            } \
            unsigned r2 = (unsigned)f2bf(m0) | ((unsigned)f2bf(m1) << 16); \
            *(unsigned*)(poolOut + ((size_t)b * NP + nbase + nl) * 512 + chofs + cobg + c2) = r2; \
        } \
    } \
}

#define ITV_OF(PH) ((PH) / G)

template<int CIN, int COUT_T, int SROWS, int NW, int NS, int G, bool POOL, bool ST, bool PRE>
__global__ __launch_bounds__(320)
void mconv(const bf16_t* __restrict__ H, const bf16_t* __restrict__ Wb,
           bf16_t* __restrict__ Yout, bf16_t* __restrict__ poolOut,
           int chofs, float* __restrict__ stats) {
    constexpr int SR = NW * 32;
    constexpr int NKK = CIN / 32;
    constexpr int NBUF = (NS * G > 1) ? 2 : 1;
    __shared__ bf16_t ytile[NBUF][SR][68];
    __shared__ float redS[NW][64];
    __shared__ float redQ[NW][64];
    const int tid  = threadIdx.x;
    const int lane = tid & 63, col = lane & 15, quad = lane >> 4, q8 = quad * 8;
    const int w    = tid >> 6;
    const int cob  = blockIdx.y * (64 * G);
    const int b    = blockIdx.z;

    // per-thread BN-stat accumulators (channel fixed per thread; see loops)
    float svA[G], svB[G], qvA[G], qvB[G];              // POOL path (per group)
#pragma unroll
    for (int g = 0; g < G; ++g) { svA[g] = 0.f; svB[g] = 0.f; qvA[g] = 0.f; qvB[g] = 0.f; }
    float sv0 = 0.f, sv1 = 0.f, sv2 = 0.f, sv3 = 0.f;  // ST (L5) path
    float qv0 = 0.f, qv1 = 0.f, qv2 = 0.f, qv3 = 0.f;

    if constexpr (PRE) {
        // A fragments, statically-indexed arrays (loop-invariant weights),
        // one set per channel group
        short8_t Af0[G][NKK], Af1[G][NKK], Af2[G][NKK], Af3[G][NKK];
#pragma unroll
        for (int g = 0; g < G; ++g) {
            const bf16_t* wpg = Wb + (size_t)(cob + g * 64 + col) * CIN + q8;
#pragma unroll
            for (int kk = 0; kk < NKK; ++kk) {
                Af0[g][kk] = *(const short8_t*)(wpg + kk * 32);
                Af1[g][kk] = *(const short8_t*)(wpg + 16 * CIN + kk * 32);
                Af2[g][kk] = *(const short8_t*)(wpg + 32 * CIN + kk * 32);
                Af3[g][kk] = *(const short8_t*)(wpg + 48 * CIN + kk * 32);
            }
        }

        // B-fragment double buffer: cur + next
        short8_t cb0[NKK], cb1[NKK], nb0[NKK], nb1[NKK];
        {
            const int sb = blockIdx.x * (SR * NS) + w * 32;
            const bf16_t* hp0 = H + ((size_t)b * SROWS + sb + col) * CIN + q8;
            const bf16_t* hp1 = hp0 + 16 * CIN;
#pragma unroll
            for (int kk = 0; kk < NKK; ++kk) {
                cb0[kk] = *(const short8_t*)(hp0 + kk * 32);
                cb1[kk] = *(const short8_t*)(hp1 + kk * 32);
            }
        }

#pragma unroll 1
        for (int it = 0; it < NS; ++it) {
            // prefetch next tile's B frags; lands under G group phases
            if (it + 1 < NS) {
                const int sb = blockIdx.x * (SR * NS) + (it + 1) * SR + w * 32;
                const bf16_t* hp0 = H + ((size_t)b * SROWS + sb + col) * CIN + q8;
                const bf16_t* hp1 = hp0 + 16 * CIN;
#pragma unroll
                for (int kk = 0; kk < NKK; ++kk) {
                    nb0[kk] = *(const short8_t*)(hp0 + kk * 32);
                    nb1[kk] = *(const short8_t*)(hp1 + kk * 32);
                }
            }

#pragma unroll
            for (int g = 0; g < G; ++g) {
                f32x4 c00 = {0.f,0.f,0.f,0.f}, c10 = c00, c20 = c00, c30 = c00;
                f32x4 c01 = c00, c11 = c00, c21 = c00, c31 = c00;
#pragma unroll
                for (int kk = 0; kk < NKK; ++kk) {
                    MF(Af0[g][kk], cb0[kk], c00) MF(Af1[g][kk], cb0[kk], c10)
                    MF(Af2[g][kk], cb0[kk], c20) MF(Af3[g][kk], cb0[kk], c30)
                    MF(Af0[g][kk], cb1[kk], c01) MF(Af1[g][kk], cb1[kk], c11)
                    MF(Af2[g][kk], cb1[kk], c21) MF(Af3[g][kk], cb1[kk], c31)
                }
                EPILOGUE(it * G + g, g)
            }

            if (it + 1 < NS) {
#pragma unroll
                for (int kk = 0; kk < NKK; ++kk) { cb0[kk] = nb0[kk]; cb1[kk] = nb1[kk]; }
            }
        }
    } else {
        // L5 (G=1): K-loop register double-buffer
        for (int it = 0; it < NS; ++it) {
            const int sb = blockIdx.x * (SR * NS) + it * SR + w * 32;
            const bf16_t* wp = Wb + (size_t)(cob + col) * CIN + q8;
            const bf16_t* hp0 = H + ((size_t)b * SROWS + sb + col) * CIN + q8;
            const bf16_t* hp1 = hp0 + 16 * CIN;

            f32x4 c00 = {0.f,0.f,0.f,0.f}, c10 = c00, c20 = c00, c30 = c00;
            f32x4 c01 = c00, c11 = c00, c21 = c00, c31 = c00;

            short8_t a0c = *(const short8_t*)(wp);
            short8_t a1c = *(const short8_t*)(wp + 16 * CIN);
            short8_t a2c = *(const short8_t*)(wp + 32 * CIN);
            short8_t a3c = *(const short8_t*)(wp + 48 * CIN);
            short8_t b0c = *(const short8_t*)(hp0);
            short8_t b1c = *(const short8_t*)(hp1);

#pragma unroll 1
            for (int k0 = 0; k0 < CIN; k0 += 32) {
                short8_t a0n, a1n, a2n, a3n, b0n, b1n;
                if (k0 + 32 < CIN) {
                    a0n = *(const short8_t*)(wp + k0 + 32);
                    a1n = *(const short8_t*)(wp + 16 * CIN + k0 + 32);
                    a2n = *(const short8_t*)(wp + 32 * CIN + k0 + 32);
                    a3n = *(const short8_t*)(wp + 48 * CIN + k0 + 32);
                    b0n = *(const short8_t*)(hp0 + k0 + 32);
                    b1n = *(const short8_t*)(hp1 + k0 + 32);
                }
                MF(a0c, b0c, c00) MF(a1c, b0c, c10) MF(a2c, b0c, c20) MF(a3c, b0c, c30)
                MF(a0c, b1c, c01) MF(a1c, b1c, c11) MF(a2c, b1c, c21) MF(a3c, b1c, c31)
                if (k0 + 32 < CIN) {
                    a0c = a0n; a1c = a1n; a2c = a2n; a3c = a3n;
                    b0c = b0n; b1c = b1n;
                }
            }

            EPILOGUE(it, 0)
        }
    }

    // ---- BN-stat wave reduction -> redS/redQ -> global atomics ----
    if constexpr (POOL) {
#pragma unroll
        for (int g = 0; g < G; ++g) {
            float sA = svA[g] + __shfl_xor(svA[g], 32, 64);
            float qA = qvA[g] + __shfl_xor(qvA[g], 32, 64);
            float sB = svB[g] + __shfl_xor(svB[g], 32, 64);
            float qB = qvB[g] + __shfl_xor(qvB[g], 32, 64);
            if (lane < 32) {
                const int c2 = lane * 2;
                redS[w][c2] = sA; redS[w][c2 + 1] = sB;
                redQ[w][c2] = qA; redQ[w][c2 + 1] = qB;
            }
            __syncthreads();
            if (tid < 64) {
                float sv = 0.f, qv = 0.f;
#pragma unroll
                for (int ch = 0; ch < NW; ++ch) { sv += redS[ch][tid]; qv += redQ[ch][tid]; }
                atomicAdd(&stats[cob + g * 64 + tid], sv);
                atomicAdd(&stats[COUT_T + cob + g * 64 + tid], qv);
            }
            if (g + 1 < G) __syncthreads();
        }
    } else if constexpr (ST) {
        // thread's channel quad: c4=(lane&15)*4; lanes differing in bits 4,5 share it
        sv0 += __shfl_xor(sv0, 16, 64); qv0 += __shfl_xor(qv0, 16, 64);
        sv1 += __shfl_xor(sv1, 16, 64); qv1 += __shfl_xor(qv1, 16, 64);
        sv2 += __shfl_xor(sv2, 16, 64); qv2 += __shfl_xor(qv2, 16, 64);
        sv3 += __shfl_xor(sv3, 16, 64); qv3 += __shfl_xor(qv3, 16, 64);
        sv0 += __shfl_xor(sv0, 32, 64); qv0 += __shfl_xor(qv0, 32, 64);
        sv1 += __shfl_xor(sv1, 32, 64); qv1 += __shfl_xor(qv1, 32, 64);
        sv2 += __shfl_xor(sv2, 32, 64); qv2 += __shfl_xor(qv2, 32, 64);
        sv3 += __shfl_xor(sv3, 32, 64); qv3 += __shfl_xor(qv3, 32, 64);
        if (lane < 16) {
            const int c4 = lane * 4;
            redS[w][c4]     = sv0; redS[w][c4 + 1] = sv1;
            redS[w][c4 + 2] = sv2; redS[w][c4 + 3] = sv3;
            redQ[w][c4]     = qv0; redQ[w][c4 + 1] = qv1;
            redQ[w][c4 + 2] = qv2; redQ[w][c4 + 3] = qv3;
        }
        __syncthreads();
        if (tid < 64) {
            float sv = 0.f, qv = 0.f;
#pragma unroll
            for (int ch = 0; ch < NW; ++ch) { sv += redS[ch][tid]; qv += redQ[ch][tid]; }
            atomicAdd(&stats[cob + tid], sv);
            atomicAdd(&stats[COUT_T + cob + tid], qv);
        }
    }
}

// ==== summed stats -> BN affine coefs ====
__global__ void bn_finalize(const float* __restrict__ stats,
                            const float* __restrict__ g, const float* __restrict__ bt,
                            float* __restrict__ ab, int C, float invM) {
    int c = blockIdx.x * 64 + threadIdx.x;
    if (c >= C) return;
    float mean = stats[c] * invM;
    float var  = fmaxf(stats[C + c] * invM - mean * mean, 0.f);
    float a = g[c] * rsqrtf(var + 1e-5f);
    ab[c] = a;
    ab[C + c] = fmaf(-mean, a, bt[c]);
}

// ==== pooled raw bf16 -> BN+ReLU -> xcat bf16 [b][n][512] ====
__global__ void pool_convert(const bf16_t* __restrict__ pr, const float* __restrict__ ab,
                             bf16_t* __restrict__ xc, int C, int chofs, int logC) {
    int t = blockIdx.x * 256 + threadIdx.x;
    int c = t & (C - 1);
    int rest = t >> logC;
    int n = rest & (NP - 1);
    int b = rest >> 11;
    size_t p = ((size_t)b * NP + n) * 512 + chofs + c;
    float v = bf2f(pr[p]);
    xc[p] = f2bf(fmaxf(fmaf(ab[c], v, ab[C + c]), 0.f));
}

// ==== out: LDS-transpose tile (R13). Block = 32 n x 512 c (64 KB LDS). ====
__global__ __launch_bounds__(256) void out_kernel(const bf16_t* __restrict__ y5,
                                                  const float* __restrict__ ab,
                                                  float* __restrict__ out) {
    __shared__ float lds[32][512];
    const int t  = threadIdx.x;
    const int nb = blockIdx.x * 32;
    const int b  = blockIdx.y;
#pragma unroll
    for (int k = 0; k < 8; ++k) {
        int ch  = t + k * 256;        // 0..2047
        int row = ch >> 6;            // 0..31
        int c8  = (ch & 63) * 8;      // 0..504
        const bf16_t* yp = y5 + ((size_t)b * NP + nb + row) * 512 + c8;
        ushort4 u0 = *(const ushort4*)(yp);
        ushort4 u1 = *(const ushort4*)(yp + 4);
        float4 a0 = *(const float4*)(ab + c8);
        float4 a1 = *(const float4*)(ab + c8 + 4);
        float4 d0 = *(const float4*)(ab + 512 + c8);
        float4 d1 = *(const float4*)(ab + 512 + c8 + 4);
        lds[row][c8 + 0] = fmaxf(fmaf(a0.x, bf2f(u0.x), d0.x), 0.f);
        lds[row][c8 + 1] = fmaxf(fmaf(a0.y, bf2f(u0.y), d0.y), 0.f);
        lds[row][c8 + 2] = fmaxf(fmaf(a0.z, bf2f(u0.z), d0.z), 0.f);
        lds[row][c8 + 3] = fmaxf(fmaf(a0.w, bf2f(u0.w), d0.w), 0.f);
        lds[row][c8 + 4] = fmaxf(fmaf(a1.x, bf2f(u1.x), d1.x), 0.f);
        lds[row][c8 + 5] = fmaxf(fmaf(a1.y, bf2f(u1.y), d1.y), 0.f);
        lds[row][c8 + 6] = fmaxf(fmaf(a1.z, bf2f(u1.z), d1.z), 0.f);
        lds[row][c8 + 7] = fmaxf(fmaf(a1.w, bf2f(u1.w), d1.w), 0.f);
    }
    __syncthreads();
    const int n4   = t & 7;           // float4 index along n (covers 32 n)
    const int crow = t >> 3;          // 0..31
#pragma unroll
    for (int cc = 0; cc < 16; ++cc) {
        int c = crow + cc * 32;
        float4 v;
        v.x = lds[n4 * 4 + 0][c];
        v.y = lds[n4 * 4 + 1][c];
        v.z = lds[n4 * 4 + 2][c];
        v.w = lds[n4 * 4 + 3][c];
        *(float4*)(out + ((size_t)b * 1024 + c) * NP + nb + n4 * 4) = v;
    }
}

// ==== zero-fill out channels 512..1023 (33.5 MB float4 stream) ====
__global__ void zout_kernel(float* __restrict__ out) {
    size_t idx4 = (size_t)blockIdx.x * 256 + threadIdx.x;
    size_t off  = idx4 * 4;                       // float offset in pad region
    size_t per_b = (size_t)512 * NP;
    size_t b = off / per_b;
    size_t r = off - b * per_b;
    float4 z = make_float4(0.f, 0.f, 0.f, 0.f);
    *(float4*)(out + (b * 1024 + 512) * NP + r) = z;
}

extern "C" void kernel_launch(void* const* d_in, const int* in_sizes, int n_in,
                              void* d_out, int out_size, void* d_ws, size_t ws_size,
                              hipStream_t stream) {
    (void)in_sizes; (void)n_in; (void)out_size; (void)ws_size;
    const float* x  = (const float*)d_in[0];
    const float* W1 = (const float*)d_in[1];
    const float* W2 = (const float*)d_in[2];
    const float* W3 = (const float*)d_in[3];
    const float* W4 = (const float*)d_in[4];
    const float* W5 = (const float*)d_in[5];
    const float* g1 = (const float*)d_in[6];  const float* b1 = (const float*)d_in[7];
    const float* g2 = (const float*)d_in[8];  const float* b2 = (const float*)d_in[9];
    const float* g3 = (const float*)d_in[10]; const float* b3 = (const float*)d_in[11];
    const float* g4 = (const float*)d_in[12]; const float* b4 = (const float*)d_in[13];
    const float* g5 = (const float*)d_in[14]; const float* b5 = (const float*)d_in[15];

    // workspace, lifetime-aliased (R9 arena):
    // A @0: f | y2 | y5(bf16)   B @41943040: y1 | y3
    char* ws = (char*)d_ws;
    bf16_t* f    = (bf16_t*)(ws + 0);
    bf16_t* y2   = (bf16_t*)(ws + 0);
    bf16_t* y5   = (bf16_t*)(ws + 0);
    bf16_t* y1   = (bf16_t*)(ws + 41943040);
    bf16_t* y3   = (bf16_t*)(ws + 41943040);
    bf16_t* poolraw = (bf16_t*)(ws + 125829120);
    bf16_t* xcat    = (bf16_t*)(ws + 142606336);
    bf16_t* Wball   = (bf16_t*)(ws + 159383552);
    bf16_t* W1b = Wball;            // 64x32
    bf16_t* W2b = Wball + 2048;     // 64x64
    bf16_t* W3b = Wball + 6144;     // 128x64
    bf16_t* W4b = Wball + 14336;    // 256x128
    bf16_t* W5b = Wball + 47104;    // 512x512
    float* stats = (float*)(ws + 160002048);
    float* ab    = (float*)(ws + 160010240);
    int*  idx    = (int*)  (ws + 160018432);

    float* st1 = stats;        float* st2 = stats + 128;  float* st3 = stats + 256;
    float* st4 = stats + 512;  float* st5 = stats + 1024;
    float* ab1 = ab;       float* ab2 = ab + 128;  float* ab3 = ab + 256;
    float* ab4 = ab + 512; float* ab5 = ab + 1024;
    const float invM14 = 1.f / (float)(BB * SS);
    const float invM5  = 1.f / (float)(BB * NP);

    zstats_kernel<<<8, 256, 0, stream>>>(stats);
    wconv_kernel<<<8,    256, 0, stream>>>(W1, W1b, 64, 6, 32);
    wconv_kernel<<<16,   256, 0, stream>>>(W2, W2b, 64, 64, 64);
    wconv_kernel<<<32,   256, 0, stream>>>(W3, W3b, 128, 64, 64);
    wconv_kernel<<<128,  256, 0, stream>>>(W4, W4b, 256, 128, 128);
    wconv_kernel<<<1024, 256, 0, stream>>>(W5, W5b, 512, 512, 512);

    knn_kernel<<<1024, 256, 0, stream>>>(x, idx);
    gather_kernel<<<dim3(160, BB), 256, 0, stream>>>(x, idx, f);

    // zero-pad half of out early (independent of everything else)
    zout_kernel<<<8192, 256, 0, stream>>>((float*)d_out);

    // L1: 6(pad32) -> 64   (G=1, NS=8)
    mconv<32, 64, SS, 5, 8, 1, true, true, true><<<dim3(32, 1, BB), 320, 0, stream>>>(
        f, W1b, y1, poolraw, 0, st1);
    bn_finalize<<<1, 64, 0, stream>>>(st1, g1, b1, ab1, 64, invM14);
    pool_convert<<<4096, 256, 0, stream>>>(poolraw, ab1, xcat, 64, 0, 6);
    bnrelu_kernel<<<10240, 256, 0, stream>>>(y1, ab1, 64);

    // L2: 64 -> 64   (G=1, NS=8)
    mconv<64, 64, SS, 5, 8, 1, true, true, true><<<dim3(32, 1, BB), 320, 0, stream>>>(
        y1, W2b, y2, poolraw, 64, st2);
    bn_finalize<<<1, 64, 0, stream>>>(st2, g2, b2, ab2, 64, invM14);
    pool_convert<<<4096, 256, 0, stream>>>(poolraw, ab2, xcat, 64, 64, 6);
    bnrelu_kernel<<<10240, 256, 0, stream>>>(y2, ab2, 64);

    // L3: 64 -> 128  (G=2 fold: one block computes both 64-ch groups)
    mconv<64, 128, SS, 5, 8, 2, true, true, true><<<dim3(32, 1, BB), 320, 0, stream>>>(
        y2, W3b, y3, poolraw, 128, st3);
    bn_finalize<<<2, 64, 0, stream>>>(st3, g3, b3, ab3, 128, invM14);
    pool_convert<<<8192, 256, 0, stream>>>(poolraw, ab3, xcat, 128, 128, 7);
    bnrelu_kernel<<<20480, 256, 0, stream>>>(y3, ab3, 128);

    // L4: 128 -> 256, pool-only (G=2 fold, grid.y=2)
    mconv<128, 256, SS, 5, 8, 2, true, false, true><<<dim3(32, 2, BB), 320, 0, stream>>>(
        y3, W4b, nullptr, poolraw, 256, st4);
    bn_finalize<<<4, 64, 0, stream>>>(st4, g4, b4, ab4, 256, invM14);
    pool_convert<<<16384, 256, 0, stream>>>(poolraw, ab4, xcat, 256, 256, 8);

    // L5: 512 -> 512 over [b][2048][512] (xcat already post-BN)
    mconv<512, 512, NP, 4, 1, 1, false, true, false><<<dim3(16, 8, BB), 256, 0, stream>>>(
        xcat, W5b, y5, nullptr, 0, st5);
    bn_finalize<<<8, 64, 0, stream>>>(st5, g5, b5, ab5, 512, invM5);

    out_kernel<<<dim3(64, BB), 256, 0, stream>>>(y5, ab5, (float*)d_out);
}

// Round 16
// 417.671 us; speedup vs baseline: 1.0472x; 1.0472x over previous
//
#include <hip/hip_runtime.h>

#define BB  8
#define NP  2048
#define KNB 20
#define KP  10      // reduced ripple depth (validity-checked, exact fallback)
#define SS  40960   // spatial per batch, layers 1-4

typedef unsigned short bf16_t;
typedef __attribute__((ext_vector_type(8))) short short8_t;   // MFMA A/B frag (8 bf16)
typedef __attribute__((ext_vector_type(4))) float f32x4;      // MFMA C/D frag

static __device__ __forceinline__ float bf2f(unsigned short u) {
    return __uint_as_float(((unsigned)u) << 16);
}
static __device__ __forceinline__ bf16_t f2bf(float f) {
    unsigned u = __float_as_uint(f);
    return (bf16_t)((u + 0x7fffu + ((u >> 16) & 1u)) >> 16);   // RNE
}

#if __has_builtin(__builtin_amdgcn_fmed3f)
#define MED3(a, b, c) __builtin_amdgcn_fmed3f((a), (b), (c))
#else
#define MED3(a, b, c) fmaxf(fminf((a), (b)), fminf(fmaxf((a), (b)), (c)))
#endif

// ==== kNN v4 (KP=10, R9-verified) ====
static __device__ __forceinline__ float negdist(float4 me, float4 p) {
    float d = me.x * p.x + me.y * p.y + me.z * p.z;
    return 2.0f * d - me.w - p.w;
}

#define BDECL(t) float bv##t = -3.4e38f;
#define MCH(t, p) bv##t = MED3(v, bv##p, bv##t);
#define BSHIFT(t, n) bv##t = bv##n;
#define FDECL(t) float fv##t = -3.4e38f;
#define FMCH(t, p) fv##t = MED3(v, fv##p, fv##t);
#define FSHIFT(t, n) fv##t = fv##n;

__global__ __launch_bounds__(256) void knn_kernel(const float* __restrict__ x,
                                                  int* __restrict__ idx) {
    __shared__ float4 tile[2064];      // 2048 + (j>>7) swizzle pad, 33 KB
    __shared__ int   cnt[16];
    __shared__ float svv[16][44];
    __shared__ int   svj[16][44];
    const int tid  = threadIdx.x;
    const int b    = blockIdx.x >> 7;
    const int pblk = blockIdx.x & 127;
    const int pl   = tid >> 4;         // local point 0..15
    const int seg  = tid & 15;         // segment 0..15 (128 cands each)
    const int i    = pblk * 16 + pl;
    const float* xb = x + (size_t)b * 3 * NP;

    for (int j = tid; j < NP; j += 256) {
        float a0 = xb[j], a1 = xb[NP + j], a2 = xb[2 * NP + j];
        tile[j + (j >> 7)] = make_float4(a0, a1, a2, a0 * a0 + a1 * a1 + a2 * a2);
    }
    if (tid < 16) cnt[tid] = 0;
    __syncthreads();
    const float4 me = tile[i + (i >> 7)];
    const float4* tseg = &tile[seg * 129];

    // ---- phase 1: per-lane top-KP VALUES, depth-10 med3 ripple ----
    BDECL(0) BDECL(1) BDECL(2) BDECL(3) BDECL(4)
    BDECL(5) BDECL(6) BDECL(7) BDECL(8) BDECL(9)
    for (int t = 0; t < 128; ++t) {
        float v = negdist(me, tseg[t]);
        MCH(9,8) MCH(8,7) MCH(7,6) MCH(6,5) MCH(5,4)
        MCH(4,3) MCH(3,2) MCH(2,1) MCH(1,0)
        bv0 = fmaxf(bv0, v);
    }

    // ---- theta: 20 rounds of 16-lane argmax-with-pop (values only) ----
    float theta = -3.4e38f;
    int pops = 0;
    for (int r = 0; r < KNB; ++r) {
        float mv = bv0; int ms = seg;
#pragma unroll
        for (int s = 1; s <= 8; s <<= 1) {
            float ov = __shfl_xor(mv, s, 64);
            int   os = __shfl_xor(ms, s, 64);
            if (ov > mv || (ov == mv && os < ms)) { mv = ov; ms = os; }
        }
        if (seg == ms) {   // exactly one lane of the 16-group pops its head
            BSHIFT(0,1) BSHIFT(1,2) BSHIFT(2,3) BSHIFT(3,4) BSHIFT(4,5)
            BSHIFT(5,6) BSHIFT(6,7) BSHIFT(7,8) BSHIFT(8,9)
            bv9 = -3.4e38f;
            ++pops;
        }
        theta = mv;        // after round 19: the 20th-largest value
    }

    // ---- validity: a fully-drained lane may have corrupted later pops ----
    int bad = (pops >= KP) ? 1 : 0;
#pragma unroll
    for (int s = 1; s <= 8; s <<= 1) bad |= __shfl_xor(bad, s, 64);
    if (bad) {             // rare (~3e-6/point): exact full-depth redo
        FDECL(0)  FDECL(1)  FDECL(2)  FDECL(3)  FDECL(4)
        FDECL(5)  FDECL(6)  FDECL(7)  FDECL(8)  FDECL(9)
        FDECL(10) FDECL(11) FDECL(12) FDECL(13) FDECL(14)
        FDECL(15) FDECL(16) FDECL(17) FDECL(18) FDECL(19)
        for (int t = 0; t < 128; ++t) {
            float v = negdist(me, tseg[t]);
            FMCH(19,18) FMCH(18,17) FMCH(17,16) FMCH(16,15) FMCH(15,14)
            FMCH(14,13) FMCH(13,12) FMCH(12,11) FMCH(11,10) FMCH(10,9)
            FMCH(9,8)   FMCH(8,7)   FMCH(7,6)   FMCH(6,5)   FMCH(5,4)
            FMCH(4,3)   FMCH(3,2)   FMCH(2,1)   FMCH(1,0)
            fv0 = fmaxf(fv0, v);
        }
        theta = -3.4e38f;
        for (int r = 0; r < KNB; ++r) {
            float mv = fv0; int ms = seg;
#pragma unroll
            for (int s = 1; s <= 8; s <<= 1) {
                float ov = __shfl_xor(mv, s, 64);
                int   os = __shfl_xor(ms, s, 64);
                if (ov > mv || (ov == mv && os < ms)) { mv = ov; ms = os; }
            }
            if (seg == ms) {
                FSHIFT(0,1)   FSHIFT(1,2)   FSHIFT(2,3)   FSHIFT(3,4)   FSHIFT(4,5)
                FSHIFT(5,6)   FSHIFT(6,7)   FSHIFT(7,8)   FSHIFT(8,9)   FSHIFT(9,10)
                FSHIFT(10,11) FSHIFT(11,12) FSHIFT(12,13) FSHIFT(13,14) FSHIFT(14,15)
                FSHIFT(15,16) FSHIFT(16,17) FSHIFT(17,18) FSHIFT(18,19)
                fv19 = -3.4e38f;
            }
            theta = mv;
        }
    }

    // ---- phase 2: collect survivors (v >= theta), identical arithmetic ----
    for (int t = 0; t < 128; ++t) {
        float v = negdist(me, tseg[t]);
        if (v >= theta) {
            int k = atomicAdd(&cnt[pl], 1);
            if (k < 44) { svv[pl][k] = v; svj[pl][k] = seg * 128 + t; }
        }
    }
    __syncthreads();

    // ---- emit: rank = #{(v',j') : v'>v or (v'==v && j'<j)} ----
    int n = cnt[pl]; if (n > 44) n = 44;
    int* o = idx + ((size_t)b * NP + i) * KNB;
    for (int e = seg; e < n; e += 16) {
        float v = svv[pl][e]; int j = svj[pl][e];
        int rank = 0;
        for (int q = 0; q < n; ++q) {
            float vq = svv[pl][q]; int jq = svj[pl][q];
            rank += (vq > v || (vq == v && jq < j)) ? 1 : 0;
        }
        if (rank < KNB) o[rank] = j;
    }
}

// ==== graph feature, channel-contiguous f[b][s][32]; ch 0-5 real, 6-31 ZERO ====
__global__ void gather_kernel(const float* __restrict__ x, const int* __restrict__ idx,
                              bf16_t* __restrict__ f) {
    int s = blockIdx.x * 256 + threadIdx.x;
    int b = blockIdx.y;
    int n = s / KNB;
    int j = idx[(size_t)b * SS + s];
    const float* xb = x + (size_t)b * 3 * NP;
    ushort4 u0, u1;
    u0.x = f2bf(xb[j]);          u0.y = f2bf(xb[NP + j]);
    u0.z = f2bf(xb[2 * NP + j]); u0.w = f2bf(xb[n]);
    u1.x = f2bf(xb[NP + n]);     u1.y = f2bf(xb[2 * NP + n]);
    u1.z = 0; u1.w = 0;
    ushort4 z4; z4.x = 0; z4.y = 0; z4.z = 0; z4.w = 0;
    bf16_t* fb = f + ((size_t)b * SS + s) * 32;
    *(ushort4*)(fb)      = u0;
    *(ushort4*)(fb + 4)  = u1;
    *(ushort4*)(fb + 8)  = z4;
    *(ushort4*)(fb + 12) = z4;
    *(ushort4*)(fb + 16) = z4;
    *(ushort4*)(fb + 20) = z4;
    *(ushort4*)(fb + 24) = z4;
    *(ushort4*)(fb + 28) = z4;
}

// ==== weights fp32 -> bf16, zero-padded rows ====
__global__ void wconv_kernel(const float* __restrict__ src, bf16_t* __restrict__ dst,
                             int O, int CI, int CIP) {
    int t = blockIdx.x * 256 + threadIdx.x;
    if (t >= O * CIP) return;
    int o = t / CIP, cp = t - o * CIP;
    dst[t] = (cp < CI) ? f2bf(src[o * CI + cp]) : (bf16_t)0;
}

// ==== zero the layer-stats accumulators (2048 floats) ====
__global__ void zstats_kernel(float* __restrict__ p) {
    p[blockIdx.x * 256 + threadIdx.x] = 0.f;
}

// ==== elementwise BN+ReLU in place on bf16 activations [.., C contiguous] ====
__global__ void bnrelu_kernel(bf16_t* __restrict__ y, const float* __restrict__ ab,
                              int C) {
    size_t e0 = ((size_t)blockIdx.x * 256 + threadIdx.x) * 8;
    int c0 = (int)(e0 & (size_t)(C - 1));
    uint4 r = *(uint4*)(y + e0);
    float4 a0 = *(const float4*)(ab + c0);
    float4 a1 = *(const float4*)(ab + c0 + 4);
    float4 d0 = *(const float4*)(ab + C + c0);
    float4 d1 = *(const float4*)(ab + C + c0 + 4);
    float v0 = bf2f((unsigned short)(r.x & 0xffffu)), v1 = bf2f((unsigned short)(r.x >> 16));
    float v2 = bf2f((unsigned short)(r.y & 0xffffu)), v3 = bf2f((unsigned short)(r.y >> 16));
    float v4 = bf2f((unsigned short)(r.z & 0xffffu)), v5 = bf2f((unsigned short)(r.z >> 16));
    float v6 = bf2f((unsigned short)(r.w & 0xffffu)), v7 = bf2f((unsigned short)(r.w >> 16));
    v0 = fmaxf(fmaf(a0.x, v0, d0.x), 0.f); v1 = fmaxf(fmaf(a0.y, v1, d0.y), 0.f);
    v2 = fmaxf(fmaf(a0.z, v2, d0.z), 0.f); v3 = fmaxf(fmaf(a0.w, v3, d0.w), 0.f);
    v4 = fmaxf(fmaf(a1.x, v4, d1.x), 0.f); v5 = fmaxf(fmaf(a1.y, v5, d1.y), 0.f);
    v6 = fmaxf(fmaf(a1.z, v6, d1.z), 0.f); v7 = fmaxf(fmaf(a1.w, v7, d1.w), 0.f);
    r.x = (unsigned)f2bf(v0) | ((unsigned)f2bf(v1) << 16);
    r.y = (unsigned)f2bf(v2) | ((unsigned)f2bf(v3) << 16);
    r.z = (unsigned)f2bf(v4) | ((unsigned)f2bf(v5) << 16);
    r.w = (unsigned)f2bf(v6) | ((unsigned)f2bf(v7) << 16);
    *(uint4*)(y + e0) = r;
}

// ==== MFMA conv: R16 = R14 structure (reg B-prefetch, ping-pong ytile,
// lgkm-only barrier, rolled NS loop, L5 K-loop dbuf) + max-NS grids:
// L3 NS=16 (grid 16x2x8=256 blocks), L4 NS=32 (grid 8x4x8=256 blocks) —
// exactly 1 block/CU, amortizing the per-block prologue P (~4.3k cyc,
// model fitted from R8/R12/R15) one more 2x. R15's G-fold is REVERTED
// (phase-count, not B-load count, is the cost; folding added serialization).
#define MF(A, B, C) C = __builtin_amdgcn_mfma_f32_16x16x32_bf16(A, B, C, 0, 0, 0);

#define LGKM_BARRIER() { \
    asm volatile("s_waitcnt lgkmcnt(0)" ::: "memory"); \
    __builtin_amdgcn_s_barrier(); \
    asm volatile("" ::: "memory"); }

#define TILE1(CC, CT, STt, YT) { \
    ushort4 t4; \
    t4.x = f2bf(CC[0]); t4.y = f2bf(CC[1]); \
    t4.z = f2bf(CC[2]); t4.w = f2bf(CC[3]); \
    *(ushort4*)&YT[w * 32 + (STt) * 16 + col][(CT) * 16 + quad * 4] = t4; }

// shared epilogue body; expects c00..c31 in scope. ONE lgkm-barrier.
#define EPILOGUE(ITV) { \
    bf16_t (*yt)[68] = ytile[(ITV) & (NBUF - 1)]; \
    TILE1(c00,0,0,yt) TILE1(c10,1,0,yt) TILE1(c20,2,0,yt) TILE1(c30,3,0,yt) \
    TILE1(c01,0,1,yt) TILE1(c11,1,1,yt) TILE1(c21,2,1,yt) TILE1(c31,3,1,yt) \
    LGKM_BARRIER() \
    if constexpr (ST) { \
        const int row0 = blockIdx.x * (SR * NS) + (ITV) * SR; \
        for (int i = tid; i < SR * 16; i += NW * 64) { \
            int row = i >> 4, c4 = (i & 15) * 4; \
            ushort4 yv = *(const ushort4*)&yt[row][c4]; \
            *(ushort4*)(Yout + ((size_t)b * SROWS + row0 + row) * COUT_T + cob + c4) = yv; \
            if constexpr (!POOL) { \
                float v0 = bf2f(yv.x), v1 = bf2f(yv.y); \
                float v2 = bf2f(yv.z), v3 = bf2f(yv.w); \
                sv0 += v0; qv0 = fmaf(v0, v0, qv0); \
                sv1 += v1; qv1 = fmaf(v1, v1, qv1); \
                sv2 += v2; qv2 = fmaf(v2, v2, qv2); \
                sv3 += v3; qv3 = fmaf(v3, v3, qv3); \
            } \
        } \
    } \
    if constexpr (POOL) { \
        const int nbase = (blockIdx.x * NS + (ITV)) * 8; \
        for (int i = tid; i < 8 * 32; i += NW * 64) { \
            const int nl = i >> 5, c2 = (i & 31) * 2; \
            float m0 = -3.4e38f, m1 = -3.4e38f; \
            _Pragma("unroll") \
            for (int k = 0; k < KNB; ++k) { \
                unsigned u = *(const unsigned*)&yt[nl * 20 + k][c2]; \
                float v0 = bf2f((unsigned short)(u & 0xffffu)); \
                float v1 = bf2f((unsigned short)(u >> 16)); \
                m0 = fmaxf(m0, v0); m1 = fmaxf(m1, v1); \
                svA += v0; qvA = fmaf(v0, v0, qvA); \
                svB += v1; qvB = fmaf(v1, v1, qvB); \
            } \
            unsigned r2 = (unsigned)f2bf(m0) | ((unsigned)f2bf(m1) << 16); \
            *(unsigned*)(poolOut + ((size_t)b * NP + nbase + nl) * 512 + chofs + cob + c2) = r2; \
        } \
    } \
}

template<int CIN, int COUT_T, int SROWS, int NW, int NS, bool POOL, bool ST, bool PRE>
__global__ __launch_bounds__(320)
void mconv(const bf16_t* __restrict__ H, const bf16_t* __restrict__ Wb,
           bf16_t* __restrict__ Yout, bf16_t* __restrict__ poolOut,
           int chofs, float* __restrict__ stats) {
    constexpr int SR = NW * 32;
    constexpr int NKK = CIN / 32;
    constexpr int NBUF = (NS > 1) ? 2 : 1;
    __shared__ bf16_t ytile[NBUF][SR][68];
    __shared__ float redS[NW][64];
    __shared__ float redQ[NW][64];
    const int tid  = threadIdx.x;
    const int lane = tid & 63, col = lane & 15, quad = lane >> 4, q8 = quad * 8;
    const int w    = tid >> 6;
    const int cob  = blockIdx.y * 64;
    const int b    = blockIdx.z;
    const bf16_t* wp = Wb + (size_t)(cob + col) * CIN + q8;

    // per-thread BN-stat accumulators (channel fixed per thread; see loops)
    float svA = 0.f, svB = 0.f, qvA = 0.f, qvB = 0.f;              // POOL path
    float sv0 = 0.f, sv1 = 0.f, sv2 = 0.f, sv3 = 0.f;              // ST (L5) path
    float qv0 = 0.f, qv1 = 0.f, qv2 = 0.f, qv3 = 0.f;

    if constexpr (PRE) {
        // A fragments, statically-indexed arrays (loop-invariant weights)
        short8_t Af0[NKK], Af1[NKK], Af2[NKK], Af3[NKK];
#pragma unroll
        for (int kk = 0; kk < NKK; ++kk) {
            Af0[kk] = *(const short8_t*)(wp + kk * 32);
            Af1[kk] = *(const short8_t*)(wp + 16 * CIN + kk * 32);
            Af2[kk] = *(const short8_t*)(wp + 32 * CIN + kk * 32);
            Af3[kk] = *(const short8_t*)(wp + 48 * CIN + kk * 32);
        }

        // B-fragment double buffer: cur + next
        short8_t cb0[NKK], cb1[NKK], nb0[NKK], nb1[NKK];
        {
            const int sb = blockIdx.x * (SR * NS) + w * 32;
            const bf16_t* hp0 = H + ((size_t)b * SROWS + sb + col) * CIN + q8;
            const bf16_t* hp1 = hp0 + 16 * CIN;
#pragma unroll
            for (int kk = 0; kk < NKK; ++kk) {
                cb0[kk] = *(const short8_t*)(hp0 + kk * 32);
                cb1[kk] = *(const short8_t*)(hp1 + kk * 32);
            }
        }

#pragma unroll 1
        for (int it = 0; it < NS; ++it) {
            // prefetch next tile's B frags; with the lgkm-only barrier these
            // stay in flight across it and land under the pool epilogue
            if (it + 1 < NS) {
                const int sb = blockIdx.x * (SR * NS) + (it + 1) * SR + w * 32;
                const bf16_t* hp0 = H + ((size_t)b * SROWS + sb + col) * CIN + q8;
                const bf16_t* hp1 = hp0 + 16 * CIN;
#pragma unroll
                for (int kk = 0; kk < NKK; ++kk) {
                    nb0[kk] = *(const short8_t*)(hp0 + kk * 32);
                    nb1[kk] = *(const short8_t*)(hp1 + kk * 32);
                }
            }

            f32x4 c00 = {0.f,0.f,0.f,0.f}, c10 = c00, c20 = c00, c30 = c00;
            f32x4 c01 = c00, c11 = c00, c21 = c00, c31 = c00;
#pragma unroll
            for (int kk = 0; kk < NKK; ++kk) {
                MF(Af0[kk], cb0[kk], c00) MF(Af1[kk], cb0[kk], c10)
                MF(Af2[kk], cb0[kk], c20) MF(Af3[kk], cb0[kk], c30)
                MF(Af0[kk], cb1[kk], c01) MF(Af1[kk], cb1[kk], c11)
                MF(Af2[kk], cb1[kk], c21) MF(Af3[kk], cb1[kk], c31)
            }

            EPILOGUE(it)

            if (it + 1 < NS) {
#pragma unroll
                for (int kk = 0; kk < NKK; ++kk) { cb0[kk] = nb0[kk]; cb1[kk] = nb1[kk]; }
            }
        }
    } else {
        // L5: K-loop register double-buffer (prefetch k0+32 while MFMA on k0)
        for (int it = 0; it < NS; ++it) {
            const int sb = blockIdx.x * (SR * NS) + it * SR + w * 32;
            const bf16_t* hp0 = H + ((size_t)b * SROWS + sb + col) * CIN + q8;
            const bf16_t* hp1 = hp0 + 16 * CIN;

            f32x4 c00 = {0.f,0.f,0.f,0.f}, c10 = c00, c20 = c00, c30 = c00;
            f32x4 c01 = c00, c11 = c00, c21 = c00, c31 = c00;

            short8_t a0c = *(const short8_t*)(wp);
            short8_t a1c = *(const short8_t*)(wp + 16 * CIN);
            short8_t a2c = *(const short8_t*)(wp + 32 * CIN);
            short8_t a3c = *(const short8_t*)(wp + 48 * CIN);
            short8_t b0c = *(const short8_t*)(hp0);
            short8_t b1c = *(const short8_t*)(hp1);

#pragma unroll 1
            for (int k0 = 0; k0 < CIN; k0 += 32) {
                short8_t a0n, a1n, a2n, a3n, b0n, b1n;
                if (k0 + 32 < CIN) {
                    a0n = *(const short8_t*)(wp + k0 + 32);
                    a1n = *(const short8_t*)(wp + 16 * CIN + k0 + 32);
                    a2n = *(const short8_t*)(wp + 32 * CIN + k0 + 32);
                    a3n = *(const short8_t*)(wp + 48 * CIN + k0 + 32);
                    b0n = *(const short8_t*)(hp0 + k0 + 32);
                    b1n = *(const short8_t*)(hp1 + k0 + 32);
                }
                MF(a0c, b0c, c00) MF(a1c, b0c, c10) MF(a2c, b0c, c20) MF(a3c, b0c, c30)
                MF(a0c, b1c, c01) MF(a1c, b1c, c11) MF(a2c, b1c, c21) MF(a3c, b1c, c31)
                if (k0 + 32 < CIN) {
                    a0c = a0n; a1c = a1n; a2c = a2n; a3c = a3n;
                    b0c = b0n; b1c = b1n;
                }
            }

            EPILOGUE(it)
        }
    }

    // ---- BN-stat wave reduction -> redS/redQ -> global atomics ----
    if constexpr (POOL) {
        // thread's channel pair: c2=(lane&31)*2; halves of the wave (nl parity)
        // combine via one xor-32 shuffle
        svA += __shfl_xor(svA, 32, 64); qvA += __shfl_xor(qvA, 32, 64);
        svB += __shfl_xor(svB, 32, 64); qvB += __shfl_xor(qvB, 32, 64);
        if (lane < 32) {
            const int c2 = lane * 2;
            redS[w][c2] = svA; redS[w][c2 + 1] = svB;
            redQ[w][c2] = qvA; redQ[w][c2 + 1] = qvB;
        }
    } else if constexpr (ST) {
        // thread's channel quad: c4=(lane&15)*4; lanes differing in bits 4,5 share it
        sv0 += __shfl_xor(sv0, 16, 64); qv0 += __shfl_xor(qv0, 16, 64);
        sv1 += __shfl_xor(sv1, 16, 64); qv1 += __shfl_xor(qv1, 16, 64);
        sv2 += __shfl_xor(sv2, 16, 64); qv2 += __shfl_xor(qv2, 16, 64);
        sv3 += __shfl_xor(sv3, 16, 64); qv3 += __shfl_xor(qv3, 16, 64);
        sv0 += __shfl_xor(sv0, 32, 64); qv0 += __shfl_xor(qv0, 32, 64);
        sv1 += __shfl_xor(sv1, 32, 64); qv1 += __shfl_xor(qv1, 32, 64);
        sv2 += __shfl_xor(sv2, 32, 64); qv2 += __shfl_xor(qv2, 32, 64);
        sv3 += __shfl_xor(sv3, 32, 64); qv3 += __shfl_xor(qv3, 32, 64);
        if (lane < 16) {
            const int c4 = lane * 4;
            redS[w][c4]     = sv0; redS[w][c4 + 1] = sv1;
            redS[w][c4 + 2] = sv2; redS[w][c4 + 3] = sv3;
            redQ[w][c4]     = qv0; redQ[w][c4 + 1] = qv1;
            redQ[w][c4 + 2] = qv2; redQ[w][c4 + 3] = qv3;
        }
    }
    __syncthreads();
    if (tid < 64) {
        float sv = 0.f, qv = 0.f;
#pragma unroll
        for (int ch = 0; ch < NW; ++ch) { sv += redS[ch][tid]; qv += redQ[ch][tid]; }
        atomicAdd(&stats[cob + tid], sv);
        atomicAdd(&stats[COUT_T + cob + tid], qv);
    }
}

// ==== summed stats -> BN affine coefs ====
__global__ void bn_finalize(const float* __restrict__ stats,
                            const float* __restrict__ g, const float* __restrict__ bt,
                            float* __restrict__ ab, int C, float invM) {
    int c = blockIdx.x * 64 + threadIdx.x;
    if (c >= C) return;
    float mean = stats[c] * invM;
    float var  = fmaxf(stats[C + c] * invM - mean * mean, 0.f);
    float a = g[c] * rsqrtf(var + 1e-5f);
    ab[c] = a;
    ab[C + c] = fmaf(-mean, a, bt[c]);
}

// ==== pooled raw bf16 -> BN+ReLU -> xcat bf16 [b][n][512] ====
__global__ void pool_convert(const bf16_t* __restrict__ pr, const float* __restrict__ ab,
                             bf16_t* __restrict__ xc, int C, int chofs, int logC) {
    int t = blockIdx.x * 256 + threadIdx.x;
    int c = t & (C - 1);
    int rest = t >> logC;
    int n = rest & (NP - 1);
    int b = rest >> 11;
    size_t p = ((size_t)b * NP + n) * 512 + chofs + c;
    float v = bf2f(pr[p]);
    xc[p] = f2bf(fmaxf(fmaf(ab[c], v, ab[C + c]), 0.f));
}

// ==== out: LDS-transpose tile (R13). Block = 32 n x 512 c (64 KB LDS). ====
__global__ __launch_bounds__(256) void out_kernel(const bf16_t* __restrict__ y5,
                                                  const float* __restrict__ ab,
                                                  float* __restrict__ out) {
    __shared__ float lds[32][512];
    const int t  = threadIdx.x;
    const int nb = blockIdx.x * 32;
    const int b  = blockIdx.y;
#pragma unroll
    for (int k = 0; k < 8; ++k) {
        int ch  = t + k * 256;        // 0..2047
        int row = ch >> 6;            // 0..31
        int c8  = (ch & 63) * 8;      // 0..504
        const bf16_t* yp = y5 + ((size_t)b * NP + nb + row) * 512 + c8;
        ushort4 u0 = *(const ushort4*)(yp);
        ushort4 u1 = *(const ushort4*)(yp + 4);
        float4 a0 = *(const float4*)(ab + c8);
        float4 a1 = *(const float4*)(ab + c8 + 4);
        float4 d0 = *(const float4*)(ab + 512 + c8);
        float4 d1 = *(const float4*)(ab + 512 + c8 + 4);
        lds[row][c8 + 0] = fmaxf(fmaf(a0.x, bf2f(u0.x), d0.x), 0.f);
        lds[row][c8 + 1] = fmaxf(fmaf(a0.y, bf2f(u0.y), d0.y), 0.f);
        lds[row][c8 + 2] = fmaxf(fmaf(a0.z, bf2f(u0.z), d0.z), 0.f);
        lds[row][c8 + 3] = fmaxf(fmaf(a0.w, bf2f(u0.w), d0.w), 0.f);
        lds[row][c8 + 4] = fmaxf(fmaf(a1.x, bf2f(u1.x), d1.x), 0.f);
        lds[row][c8 + 5] = fmaxf(fmaf(a1.y, bf2f(u1.y), d1.y), 0.f);
        lds[row][c8 + 6] = fmaxf(fmaf(a1.z, bf2f(u1.z), d1.z), 0.f);
        lds[row][c8 + 7] = fmaxf(fmaf(a1.w, bf2f(u1.w), d1.w), 0.f);
    }
    __syncthreads();
    const int n4   = t & 7;           // float4 index along n (covers 32 n)
    const int crow = t >> 3;          // 0..31
#pragma unroll
    for (int cc = 0; cc < 16; ++cc) {
        int c = crow + cc * 32;
        float4 v;
        v.x = lds[n4 * 4 + 0][c];
        v.y = lds[n4 * 4 + 1][c];
        v.z = lds[n4 * 4 + 2][c];
        v.w = lds[n4 * 4 + 3][c];
        *(float4*)(out + ((size_t)b * 1024 + c) * NP + nb + n4 * 4) = v;
    }
}

// ==== zero-fill out channels 512..1023 (33.5 MB float4 stream) ====
__global__ void zout_kernel(float* __restrict__ out) {
    size_t idx4 = (size_t)blockIdx.x * 256 + threadIdx.x;
    size_t off  = idx4 * 4;                       // float offset in pad region
    size_t per_b = (size_t)512 * NP;
    size_t b = off / per_b;
    size_t r = off - b * per_b;
    float4 z = make_float4(0.f, 0.f, 0.f, 0.f);
    *(float4*)(out + (b * 1024 + 512) * NP + r) = z;
}

extern "C" void kernel_launch(void* const* d_in, const int* in_sizes, int n_in,
                              void* d_out, int out_size, void* d_ws, size_t ws_size,
                              hipStream_t stream) {
    (void)in_sizes; (void)n_in; (void)out_size; (void)ws_size;
    const float* x  = (const float*)d_in[0];
    const float* W1 = (const float*)d_in[1];
    const float* W2 = (const float*)d_in[2];
    const float* W3 = (const float*)d_in[3];
    const float* W4 = (const float*)d_in[4];
    const float* W5 = (const float*)d_in[5];
    const float* g1 = (const float*)d_in[6];  const float* b1 = (const float*)d_in[7];
    const float* g2 = (const float*)d_in[8];  const float* b2 = (const float*)d_in[9];
    const float* g3 = (const float*)d_in[10]; const float* b3 = (const float*)d_in[11];
    const float* g4 = (const float*)d_in[12]; const float* b4 = (const float*)d_in[13];
    const float* g5 = (const float*)d_in[14]; const float* b5 = (const float*)d_in[15];

    // workspace, lifetime-aliased (R9 arena):
    // A @0: f | y2 | y5(bf16)   B @41943040: y1 | y3
    char* ws = (char*)d_ws;
    bf16_t* f    = (bf16_t*)(ws + 0);
    bf16_t* y2   = (bf16_t*)(ws + 0);
    bf16_t* y5   = (bf16_t*)(ws + 0);
    bf16_t* y1   = (bf16_t*)(ws + 41943040);
    bf16_t* y3   = (bf16_t*)(ws + 41943040);
    bf16_t* poolraw = (bf16_t*)(ws + 125829120);
    bf16_t* xcat    = (bf16_t*)(ws + 142606336);
    bf16_t* Wball   = (bf16_t*)(ws + 159383552);
    bf16_t* W1b = Wball;            // 64x32
    bf16_t* W2b = Wball + 2048;     // 64x64
    bf16_t* W3b = Wball + 6144;     // 128x64
    bf16_t* W4b = Wball + 14336;    // 256x128
    bf16_t* W5b = Wball + 47104;    // 512x512
    float* stats = (float*)(ws + 160002048);
    float* ab    = (float*)(ws + 160010240);
    int*  idx    = (int*)  (ws + 160018432);

    float* st1 = stats;        float* st2 = stats + 128;  float* st3 = stats + 256;
    float* st4 = stats + 512;  float* st5 = stats + 1024;
    float* ab1 = ab;       float* ab2 = ab + 128;  float* ab3 = ab + 256;
    float* ab4 = ab + 512; float* ab5 = ab + 1024;
    const float invM14 = 1.f / (float)(BB * SS);
    const float invM5  = 1.f / (float)(BB * NP);

    zstats_kernel<<<8, 256, 0, stream>>>(stats);
    wconv_kernel<<<8,    256, 0, stream>>>(W1, W1b, 64, 6, 32);
    wconv_kernel<<<16,   256, 0, stream>>>(W2, W2b, 64, 64, 64);
    wconv_kernel<<<32,   256, 0, stream>>>(W3, W3b, 128, 64, 64);
    wconv_kernel<<<128,  256, 0, stream>>>(W4, W4b, 256, 128, 128);
    wconv_kernel<<<1024, 256, 0, stream>>>(W5, W5b, 512, 512, 512);

    knn_kernel<<<1024, 256, 0, stream>>>(x, idx);
    gather_kernel<<<dim3(160, BB), 256, 0, stream>>>(x, idx, f);

    // zero-pad half of out early (independent of everything else)
    zout_kernel<<<8192, 256, 0, stream>>>((float*)d_out);

    // L1: 6(pad32) -> 64   (NS=8: 32 x-blocks of 1280 rows; 256 blocks)
    mconv<32, 64, SS, 5, 8, true, true, true><<<dim3(32, 1, BB), 320, 0, stream>>>(
        f, W1b, y1, poolraw, 0, st1);
    bn_finalize<<<1, 64, 0, stream>>>(st1, g1, b1, ab1, 64, invM14);
    pool_convert<<<4096, 256, 0, stream>>>(poolraw, ab1, xcat, 64, 0, 6);
    bnrelu_kernel<<<10240, 256, 0, stream>>>(y1, ab1, 64);

    // L2: 64 -> 64   (NS=8; 256 blocks)
    mconv<64, 64, SS, 5, 8, true, true, true><<<dim3(32, 1, BB), 320, 0, stream>>>(
        y1, W2b, y2, poolraw, 64, st2);
    bn_finalize<<<1, 64, 0, stream>>>(st2, g2, b2, ab2, 64, invM14);
    pool_convert<<<4096, 256, 0, stream>>>(poolraw, ab2, xcat, 64, 64, 6);
    bnrelu_kernel<<<10240, 256, 0, stream>>>(y2, ab2, 64);

    // L3: 64 -> 128  (NS=16: 16 x-blocks of 2560 rows; 256 blocks = 1/CU)
    mconv<64, 128, SS, 5, 16, true, true, true><<<dim3(16, 2, BB), 320, 0, stream>>>(
        y2, W3b, y3, poolraw, 128, st3);
    bn_finalize<<<2, 64, 0, stream>>>(st3, g3, b3, ab3, 128, invM14);
    pool_convert<<<8192, 256, 0, stream>>>(poolraw, ab3, xcat, 128, 128, 7);
    bnrelu_kernel<<<20480, 256, 0, stream>>>(y3, ab3, 128);

    // L4: 128 -> 256, pool-only (NS=32: 8 x-blocks of 5120 rows; 256 blocks)
    mconv<128, 256, SS, 5, 32, true, false, true><<<dim3(8, 4, BB), 320, 0, stream>>>(
        y3, W4b, nullptr, poolraw, 256, st4);
    bn_finalize<<<4, 64, 0, stream>>>(st4, g4, b4, ab4, 256, invM14);
    pool_convert<<<16384, 256, 0, stream>>>(poolraw, ab4, xcat, 256, 256, 8);

    // L5: 512 -> 512 over [b][2048][512] (xcat already post-BN)
    mconv<512, 512, NP, 4, 1, false, true, false><<<dim3(16, 8, BB), 256, 0, stream>>>(
        xcat, W5b, y5, nullptr, 0, st5);
    bn_finalize<<<8, 64, 0, stream>>>(st5, g5, b5, ab5, 512, invM5);

    out_kernel<<<dim3(64, BB), 256, 0, stream>>>(y5, ab5, (float*)d_out);
}

// Round 17
// 413.096 us; speedup vs baseline: 1.0588x; 1.0111x over previous
//
#include <hip/hip_runtime.h>

#define BB  8
#define NP  2048
#define KNB 20
#define KP  10      // reduced ripple depth (validity-checked, exact fallback)
#define SS  40960   // spatial per batch, layers 1-4

typedef unsigned short bf16_t;
typedef __attribute__((ext_vector_type(8))) short short8_t;   // MFMA A/B frag (8 bf16)
typedef __attribute__((ext_vector_type(4))) float f32x4;      // MFMA C/D frag

static __device__ __forceinline__ float bf2f(unsigned short u) {
    return __uint_as_float(((unsigned)u) << 16);
}
static __device__ __forceinline__ bf16_t f2bf(float f) {
    unsigned u = __float_as_uint(f);
    return (bf16_t)((u + 0x7fffu + ((u >> 16) & 1u)) >> 16);   // RNE
}

#if __has_builtin(__builtin_amdgcn_fmed3f)
#define MED3(a, b, c) __builtin_amdgcn_fmed3f((a), (b), (c))
#else
#define MED3(a, b, c) fmaxf(fminf((a), (b)), fminf(fmaxf((a), (b)), (c)))
#endif

// ==== kNN v4 (KP=10, R9-verified) ====
static __device__ __forceinline__ float negdist(float4 me, float4 p) {
    float d = me.x * p.x + me.y * p.y + me.z * p.z;
    return 2.0f * d - me.w - p.w;
}

#define BDECL(t) float bv##t = -3.4e38f;
#define MCH(t, p) bv##t = MED3(v, bv##p, bv##t);
#define BSHIFT(t, n) bv##t = bv##n;
#define FDECL(t) float fv##t = -3.4e38f;
#define FMCH(t, p) fv##t = MED3(v, fv##p, fv##t);
#define FSHIFT(t, n) fv##t = fv##n;

__global__ __launch_bounds__(256) void knn_kernel(const float* __restrict__ x,
                                                  int* __restrict__ idx) {
    __shared__ float4 tile[2064];      // 2048 + (j>>7) swizzle pad, 33 KB
    __shared__ int   cnt[16];
    __shared__ float svv[16][44];
    __shared__ int   svj[16][44];
    const int tid  = threadIdx.x;
    const int b    = blockIdx.x >> 7;
    const int pblk = blockIdx.x & 127;
    const int pl   = tid >> 4;         // local point 0..15
    const int seg  = tid & 15;         // segment 0..15 (128 cands each)
    const int i    = pblk * 16 + pl;
    const float* xb = x + (size_t)b * 3 * NP;

    for (int j = tid; j < NP; j += 256) {
        float a0 = xb[j], a1 = xb[NP + j], a2 = xb[2 * NP + j];
        tile[j + (j >> 7)] = make_float4(a0, a1, a2, a0 * a0 + a1 * a1 + a2 * a2);
    }
    if (tid < 16) cnt[tid] = 0;
    __syncthreads();
    const float4 me = tile[i + (i >> 7)];
    const float4* tseg = &tile[seg * 129];

    // ---- phase 1: per-lane top-KP VALUES, depth-10 med3 ripple ----
    BDECL(0) BDECL(1) BDECL(2) BDECL(3) BDECL(4)
    BDECL(5) BDECL(6) BDECL(7) BDECL(8) BDECL(9)
    for (int t = 0; t < 128; ++t) {
        float v = negdist(me, tseg[t]);
        MCH(9,8) MCH(8,7) MCH(7,6) MCH(6,5) MCH(5,4)
        MCH(4,3) MCH(3,2) MCH(2,1) MCH(1,0)
        bv0 = fmaxf(bv0, v);
    }

    // ---- theta: 20 rounds of 16-lane argmax-with-pop (values only) ----
    float theta = -3.4e38f;
    int pops = 0;
    for (int r = 0; r < KNB; ++r) {
        float mv = bv0; int ms = seg;
#pragma unroll
        for (int s = 1; s <= 8; s <<= 1) {
            float ov = __shfl_xor(mv, s, 64);
            int   os = __shfl_xor(ms, s, 64);
            if (ov > mv || (ov == mv && os < ms)) { mv = ov; ms = os; }
        }
        if (seg == ms) {   // exactly one lane of the 16-group pops its head
            BSHIFT(0,1) BSHIFT(1,2) BSHIFT(2,3) BSHIFT(3,4) BSHIFT(4,5)
            BSHIFT(5,6) BSHIFT(6,7) BSHIFT(7,8) BSHIFT(8,9)
            bv9 = -3.4e38f;
            ++pops;
        }
        theta = mv;        // after round 19: the 20th-largest value
    }

    // ---- validity: a fully-drained lane may have corrupted later pops ----
    int bad = (pops >= KP) ? 1 : 0;
#pragma unroll
    for (int s = 1; s <= 8; s <<= 1) bad |= __shfl_xor(bad, s, 64);
    if (bad) {             // rare (~3e-6/point): exact full-depth redo
        FDECL(0)  FDECL(1)  FDECL(2)  FDECL(3)  FDECL(4)
        FDECL(5)  FDECL(6)  FDECL(7)  FDECL(8)  FDECL(9)
        FDECL(10) FDECL(11) FDECL(12) FDECL(13) FDECL(14)
        FDECL(15) FDECL(16) FDECL(17) FDECL(18) FDECL(19)
        for (int t = 0; t < 128; ++t) {
            float v = negdist(me, tseg[t]);
            FMCH(19,18) FMCH(18,17) FMCH(17,16) FMCH(16,15) FMCH(15,14)
            FMCH(14,13) FMCH(13,12) FMCH(12,11) FMCH(11,10) FMCH(10,9)
            FMCH(9,8)   FMCH(8,7)   FMCH(7,6)   FMCH(6,5)   FMCH(5,4)
            FMCH(4,3)   FMCH(3,2)   FMCH(2,1)   FMCH(1,0)
            fv0 = fmaxf(fv0, v);
        }
        theta = -3.4e38f;
        for (int r = 0; r < KNB; ++r) {
            float mv = fv0; int ms = seg;
#pragma unroll
            for (int s = 1; s <= 8; s <<= 1) {
                float ov = __shfl_xor(mv, s, 64);
                int   os = __shfl_xor(ms, s, 64);
                if (ov > mv || (ov == mv && os < ms)) { mv = ov; ms = os; }
            }
            if (seg == ms) {
                FSHIFT(0,1)   FSHIFT(1,2)   FSHIFT(2,3)   FSHIFT(3,4)   FSHIFT(4,5)
                FSHIFT(5,6)   FSHIFT(6,7)   FSHIFT(7,8)   FSHIFT(8,9)   FSHIFT(9,10)
                FSHIFT(10,11) FSHIFT(11,12) FSHIFT(12,13) FSHIFT(13,14) FSHIFT(14,15)
                FSHIFT(15,16) FSHIFT(16,17) FSHIFT(17,18) FSHIFT(18,19)
                fv19 = -3.4e38f;
            }
            theta = mv;
        }
    }

    // ---- phase 2: collect survivors (v >= theta), identical arithmetic ----
    for (int t = 0; t < 128; ++t) {
        float v = negdist(me, tseg[t]);
        if (v >= theta) {
            int k = atomicAdd(&cnt[pl], 1);
            if (k < 44) { svv[pl][k] = v; svj[pl][k] = seg * 128 + t; }
        }
    }
    __syncthreads();

    // ---- emit: rank = #{(v',j') : v'>v or (v'==v && j'<j)} ----
    int n = cnt[pl]; if (n > 44) n = 44;
    int* o = idx + ((size_t)b * NP + i) * KNB;
    for (int e = seg; e < n; e += 16) {
        float v = svv[pl][e]; int j = svj[pl][e];
        int rank = 0;
        for (int q = 0; q < n; ++q) {
            float vq = svv[pl][q]; int jq = svj[pl][q];
            rank += (vq > v || (vq == v && jq < j)) ? 1 : 0;
        }
        if (rank < KNB) o[rank] = j;
    }
}

// ==== weights fp32 -> bf16, zero-padded rows ====
__global__ void wconv_kernel(const float* __restrict__ src, bf16_t* __restrict__ dst,
                             int O, int CI, int CIP) {
    int t = blockIdx.x * 256 + threadIdx.x;
    if (t >= O * CIP) return;
    int o = t / CIP, cp = t - o * CIP;
    dst[t] = (cp < CI) ? f2bf(src[o * CI + cp]) : (bf16_t)0;
}

// ==== zero the layer-stats accumulators (2048 floats) ====
__global__ void zstats_kernel(float* __restrict__ p) {
    p[blockIdx.x * 256 + threadIdx.x] = 0.f;
}

// ==== elementwise BN+ReLU in place on bf16 activations [.., C contiguous] ====
__global__ void bnrelu_kernel(bf16_t* __restrict__ y, const float* __restrict__ ab,
                              int C) {
    size_t e0 = ((size_t)blockIdx.x * 256 + threadIdx.x) * 8;
    int c0 = (int)(e0 & (size_t)(C - 1));
    uint4 r = *(uint4*)(y + e0);
    float4 a0 = *(const float4*)(ab + c0);
    float4 a1 = *(const float4*)(ab + c0 + 4);
    float4 d0 = *(const float4*)(ab + C + c0);
    float4 d1 = *(const float4*)(ab + C + c0 + 4);
    float v0 = bf2f((unsigned short)(r.x & 0xffffu)), v1 = bf2f((unsigned short)(r.x >> 16));
    float v2 = bf2f((unsigned short)(r.y & 0xffffu)), v3 = bf2f((unsigned short)(r.y >> 16));
    float v4 = bf2f((unsigned short)(r.z & 0xffffu)), v5 = bf2f((unsigned short)(r.z >> 16));
    float v6 = bf2f((unsigned short)(r.w & 0xffffu)), v7 = bf2f((unsigned short)(r.w >> 16));
    v0 = fmaxf(fmaf(a0.x, v0, d0.x), 0.f); v1 = fmaxf(fmaf(a0.y, v1, d0.y), 0.f);
    v2 = fmaxf(fmaf(a0.z, v2, d0.z), 0.f); v3 = fmaxf(fmaf(a0.w, v3, d0.w), 0.f);
    v4 = fmaxf(fmaf(a1.x, v4, d1.x), 0.f); v5 = fmaxf(fmaf(a1.y, v5, d1.y), 0.f);
    v6 = fmaxf(fmaf(a1.z, v6, d1.z), 0.f); v7 = fmaxf(fmaf(a1.w, v7, d1.w), 0.f);
    r.x = (unsigned)f2bf(v0) | ((unsigned)f2bf(v1) << 16);
    r.y = (unsigned)f2bf(v2) | ((unsigned)f2bf(v3) << 16);
    r.z = (unsigned)f2bf(v4) | ((unsigned)f2bf(v5) << 16);
    r.w = (unsigned)f2bf(v6) | ((unsigned)f2bf(v7) << 16);
    *(uint4*)(y + e0) = r;
}

// ==== MFMA conv: R17 = R16 + GATHER mode for L1 (the f tensor is deleted;
// L1's B fragments are built in registers at PREFETCH time from x + idx:
// row s -> channels [x(j), x(n), 0...] with j=idx[s], n=s/20. x is 24KB/batch
// (L2-resident) so the gather reads are cache hits. Only quad-0 lanes do
// work; quads 1-3 hold zero frags, bit-identical to the old zero-padded f.
// Conversions sit in the latency-hidden prefetch slot (R11 lesson: never on
// the serial nb->cb path).
#define MF(A, B, C) C = __builtin_amdgcn_mfma_f32_16x16x32_bf16(A, B, C, 0, 0, 0);

#define LGKM_BARRIER() { \
    asm volatile("s_waitcnt lgkmcnt(0)" ::: "memory"); \
    __builtin_amdgcn_s_barrier(); \
    asm volatile("" ::: "memory"); }

#define TILE1(CC, CT, STt, YT) { \
    ushort4 t4; \
    t4.x = f2bf(CC[0]); t4.y = f2bf(CC[1]); \
    t4.z = f2bf(CC[2]); t4.w = f2bf(CC[3]); \
    *(ushort4*)&YT[w * 32 + (STt) * 16 + col][(CT) * 16 + quad * 4] = t4; }

// build L1 B fragment for row r (only quad 0 nonzero; matches gather_kernel)
static __device__ __forceinline__ short8_t gfrag(const float* __restrict__ xb,
                                                 const int* __restrict__ idxb,
                                                 int r, int q8) {
    short8_t f = {0, 0, 0, 0, 0, 0, 0, 0};
    if (q8 == 0) {
        int n = r / KNB;
        int j = idxb[r];
        f[0] = (short)f2bf(xb[j]);
        f[1] = (short)f2bf(xb[NP + j]);
        f[2] = (short)f2bf(xb[2 * NP + j]);
        f[3] = (short)f2bf(xb[n]);
        f[4] = (short)f2bf(xb[NP + n]);
        f[5] = (short)f2bf(xb[2 * NP + n]);
    }
    return f;
}

// shared epilogue body; expects c00..c31 in scope. ONE lgkm-barrier.
#define EPILOGUE(ITV) { \
    bf16_t (*yt)[68] = ytile[(ITV) & (NBUF - 1)]; \
    TILE1(c00,0,0,yt) TILE1(c10,1,0,yt) TILE1(c20,2,0,yt) TILE1(c30,3,0,yt) \
    TILE1(c01,0,1,yt) TILE1(c11,1,1,yt) TILE1(c21,2,1,yt) TILE1(c31,3,1,yt) \
    LGKM_BARRIER() \
    if constexpr (ST) { \
        const int row0 = blockIdx.x * (SR * NS) + (ITV) * SR; \
        for (int i = tid; i < SR * 16; i += NW * 64) { \
            int row = i >> 4, c4 = (i & 15) * 4; \
            ushort4 yv = *(const ushort4*)&yt[row][c4]; \
            *(ushort4*)(Yout + ((size_t)b * SROWS + row0 + row) * COUT_T + cob + c4) = yv; \
            if constexpr (!POOL) { \
                float v0 = bf2f(yv.x), v1 = bf2f(yv.y); \
                float v2 = bf2f(yv.z), v3 = bf2f(yv.w); \
                sv0 += v0; qv0 = fmaf(v0, v0, qv0); \
                sv1 += v1; qv1 = fmaf(v1, v1, qv1); \
                sv2 += v2; qv2 = fmaf(v2, v2, qv2); \
                sv3 += v3; qv3 = fmaf(v3, v3, qv3); \
            } \
        } \
    } \
    if constexpr (POOL) { \
        const int nbase = (blockIdx.x * NS + (ITV)) * 8; \
        for (int i = tid; i < 8 * 32; i += NW * 64) { \
            const int nl = i >> 5, c2 = (i & 31) * 2; \
            float m0 = -3.4e38f, m1 = -3.4e38f; \
            _Pragma("unroll") \
            for (int k = 0; k < KNB; ++k) { \
                unsigned u = *(const unsigned*)&yt[nl * 20 + k][c2]; \
                float v0 = bf2f((unsigned short)(u & 0xffffu)); \
                float v1 = bf2f((unsigned short)(u >> 16)); \
                m0 = fmaxf(m0, v0); m1 = fmaxf(m1, v1); \
                svA += v0; qvA = fmaf(v0, v0, qvA); \
                svB += v1; qvB = fmaf(v1, v1, qvB); \
            } \
            unsigned r2 = (unsigned)f2bf(m0) | ((unsigned)f2bf(m1) << 16); \
            *(unsigned*)(poolOut + ((size_t)b * NP + nbase + nl) * 512 + chofs + cob + c2) = r2; \
        } \
    } \
}

template<int CIN, int COUT_T, int SROWS, int NW, int NS, bool POOL, bool ST, bool PRE, bool GATHER>
__global__ __launch_bounds__(320)
void mconv(const bf16_t* __restrict__ H, const bf16_t* __restrict__ Wb,
           bf16_t* __restrict__ Yout, bf16_t* __restrict__ poolOut,
           int chofs, float* __restrict__ stats,
           const float* __restrict__ Xg, const int* __restrict__ IdxG) {
    constexpr int SR = NW * 32;
    constexpr int NKK = CIN / 32;
    constexpr int NBUF = (NS > 1) ? 2 : 1;
    __shared__ bf16_t ytile[NBUF][SR][68];
    __shared__ float redS[NW][64];
    __shared__ float redQ[NW][64];
    const int tid  = threadIdx.x;
    const int lane = tid & 63, col = lane & 15, quad = lane >> 4, q8 = quad * 8;
    const int w    = tid >> 6;
    const int cob  = blockIdx.y * 64;
    const int b    = blockIdx.z;
    const bf16_t* wp = Wb + (size_t)(cob + col) * CIN + q8;
    const float* xb = GATHER ? (Xg + (size_t)b * 3 * NP) : nullptr;
    const int* idxb = GATHER ? (IdxG + (size_t)b * SS) : nullptr;

    // per-thread BN-stat accumulators (channel fixed per thread; see loops)
    float svA = 0.f, svB = 0.f, qvA = 0.f, qvB = 0.f;              // POOL path
    float sv0 = 0.f, sv1 = 0.f, sv2 = 0.f, sv3 = 0.f;              // ST (L5) path
    float qv0 = 0.f, qv1 = 0.f, qv2 = 0.f, qv3 = 0.f;

    if constexpr (PRE) {
        // A fragments, statically-indexed arrays (loop-invariant weights)
        short8_t Af0[NKK], Af1[NKK], Af2[NKK], Af3[NKK];
#pragma unroll
        for (int kk = 0; kk < NKK; ++kk) {
            Af0[kk] = *(const short8_t*)(wp + kk * 32);
            Af1[kk] = *(const short8_t*)(wp + 16 * CIN + kk * 32);
            Af2[kk] = *(const short8_t*)(wp + 32 * CIN + kk * 32);
            Af3[kk] = *(const short8_t*)(wp + 48 * CIN + kk * 32);
        }

        // B-fragment double buffer: cur + next
        short8_t cb0[NKK], cb1[NKK], nb0[NKK], nb1[NKK];
        {
            const int sb = blockIdx.x * (SR * NS) + w * 32;
            if constexpr (GATHER) {
                cb0[0] = gfrag(xb, idxb, sb + col, q8);
                cb1[0] = gfrag(xb, idxb, sb + col + 16, q8);
            } else {
                const bf16_t* hp0 = H + ((size_t)b * SROWS + sb + col) * CIN + q8;
                const bf16_t* hp1 = hp0 + 16 * CIN;
#pragma unroll
                for (int kk = 0; kk < NKK; ++kk) {
                    cb0[kk] = *(const short8_t*)(hp0 + kk * 32);
                    cb1[kk] = *(const short8_t*)(hp1 + kk * 32);
                }
            }
        }

#pragma unroll 1
        for (int it = 0; it < NS; ++it) {
            // prefetch next tile's B frags; with the lgkm-only barrier these
            // stay in flight across it and land under the pool epilogue
            if (it + 1 < NS) {
                const int sb = blockIdx.x * (SR * NS) + (it + 1) * SR + w * 32;
                if constexpr (GATHER) {
                    nb0[0] = gfrag(xb, idxb, sb + col, q8);
                    nb1[0] = gfrag(xb, idxb, sb + col + 16, q8);
                } else {
                    const bf16_t* hp0 = H + ((size_t)b * SROWS + sb + col) * CIN + q8;
                    const bf16_t* hp1 = hp0 + 16 * CIN;
#pragma unroll
                    for (int kk = 0; kk < NKK; ++kk) {
                        nb0[kk] = *(const short8_t*)(hp0 + kk * 32);
                        nb1[kk] = *(const short8_t*)(hp1 + kk * 32);
                    }
                }
            }

            f32x4 c00 = {0.f,0.f,0.f,0.f}, c10 = c00, c20 = c00, c30 = c00;
            f32x4 c01 = c00, c11 = c00, c21 = c00, c31 = c00;
#pragma unroll
            for (int kk = 0; kk < NKK; ++kk) {
                MF(Af0[kk], cb0[kk], c00) MF(Af1[kk], cb0[kk], c10)
                MF(Af2[kk], cb0[kk], c20) MF(Af3[kk], cb0[kk], c30)
                MF(Af0[kk], cb1[kk], c01) MF(Af1[kk], cb1[kk], c11)
                MF(Af2[kk], cb1[kk], c21) MF(Af3[kk], cb1[kk], c31)
            }

            EPILOGUE(it)

            if (it + 1 < NS) {
#pragma unroll
                for (int kk = 0; kk < NKK; ++kk) { cb0[kk] = nb0[kk]; cb1[kk] = nb1[kk]; }
            }
        }
    } else {
        // L5: K-loop register double-buffer (prefetch k0+32 while MFMA on k0)
        for (int it = 0; it < NS; ++it) {
            const int sb = blockIdx.x * (SR * NS) + it * SR + w * 32;
            const bf16_t* hp0 = H + ((size_t)b * SROWS + sb + col) * CIN + q8;
            const bf16_t* hp1 = hp0 + 16 * CIN;

            f32x4 c00 = {0.f,0.f,0.f,0.f}, c10 = c00, c20 = c00, c30 = c00;
            f32x4 c01 = c00, c11 = c00, c21 = c00, c31 = c00;

            short8_t a0c = *(const short8_t*)(wp);
            short8_t a1c = *(const short8_t*)(wp + 16 * CIN);
            short8_t a2c = *(const short8_t*)(wp + 32 * CIN);
            short8_t a3c = *(const short8_t*)(wp + 48 * CIN);
            short8_t b0c = *(const short8_t*)(hp0);
            short8_t b1c = *(const short8_t*)(hp1);

#pragma unroll 1
            for (int k0 = 0; k0 < CIN; k0 += 32) {
                short8_t a0n, a1n, a2n, a3n, b0n, b1n;
                if (k0 + 32 < CIN) {
                    a0n = *(const short8_t*)(wp + k0 + 32);
                    a1n = *(const short8_t*)(wp + 16 * CIN + k0 + 32);
                    a2n = *(const short8_t*)(wp + 32 * CIN + k0 + 32);
                    a3n = *(const short8_t*)(wp + 48 * CIN + k0 + 32);
                    b0n = *(const short8_t*)(hp0 + k0 + 32);
                    b1n = *(const short8_t*)(hp1 + k0 + 32);
                }
                MF(a0c, b0c, c00) MF(a1c, b0c, c10) MF(a2c, b0c, c20) MF(a3c, b0c, c30)
                MF(a0c, b1c, c01) MF(a1c, b1c, c11) MF(a2c, b1c, c21) MF(a3c, b1c, c31)
                if (k0 + 32 < CIN) {
                    a0c = a0n; a1c = a1n; a2c = a2n; a3c = a3n;
                    b0c = b0n; b1c = b1n;
                }
            }

            EPILOGUE(it)
        }
    }

    // ---- BN-stat wave reduction -> redS/redQ -> global atomics ----
    if constexpr (POOL) {
        // thread's channel pair: c2=(lane&31)*2; halves of the wave (nl parity)
        // combine via one xor-32 shuffle
        svA += __shfl_xor(svA, 32, 64); qvA += __shfl_xor(qvA, 32, 64);
        svB += __shfl_xor(svB, 32, 64); qvB += __shfl_xor(qvB, 32, 64);
        if (lane < 32) {
            const int c2 = lane * 2;
            redS[w][c2] = svA; redS[w][c2 + 1] = svB;
            redQ[w][c2] = qvA; redQ[w][c2 + 1] = qvB;
        }
    } else if constexpr (ST) {
        // thread's channel quad: c4=(lane&15)*4; lanes differing in bits 4,5 share it
        sv0 += __shfl_xor(sv0, 16, 64); qv0 += __shfl_xor(qv0, 16, 64);
        sv1 += __shfl_xor(sv1, 16, 64); qv1 += __shfl_xor(qv1, 16, 64);
        sv2 += __shfl_xor(sv2, 16, 64); qv2 += __shfl_xor(qv2, 16, 64);
        sv3 += __shfl_xor(sv3, 16, 64); qv3 += __shfl_xor(qv3, 16, 64);
        sv0 += __shfl_xor(sv0, 32, 64); qv0 += __shfl_xor(qv0, 32, 64);
        sv1 += __shfl_xor(sv1, 32, 64); qv1 += __shfl_xor(qv1, 32, 64);
        sv2 += __shfl_xor(sv2, 32, 64); qv2 += __shfl_xor(qv2, 32, 64);
        sv3 += __shfl_xor(sv3, 32, 64); qv3 += __shfl_xor(qv3, 32, 64);
        if (lane < 16) {
            const int c4 = lane * 4;
            redS[w][c4]     = sv0; redS[w][c4 + 1] = sv1;
            redS[w][c4 + 2] = sv2; redS[w][c4 + 3] = sv3;
            redQ[w][c4]     = qv0; redQ[w][c4 + 1] = qv1;
            redQ[w][c4 + 2] = qv2; redQ[w][c4 + 3] = qv3;
        }
    }
    __syncthreads();
    if (tid < 64) {
        float sv = 0.f, qv = 0.f;
#pragma unroll
        for (int ch = 0; ch < NW; ++ch) { sv += redS[ch][tid]; qv += redQ[ch][tid]; }
        atomicAdd(&stats[cob + tid], sv);
        atomicAdd(&stats[COUT_T + cob + tid], qv);
    }
}

// ==== summed stats -> BN affine coefs ====
__global__ void bn_finalize(const float* __restrict__ stats,
                            const float* __restrict__ g, const float* __restrict__ bt,
                            float* __restrict__ ab, int C, float invM) {
    int c = blockIdx.x * 64 + threadIdx.x;
    if (c >= C) return;
    float mean = stats[c] * invM;
    float var  = fmaxf(stats[C + c] * invM - mean * mean, 0.f);
    float a = g[c] * rsqrtf(var + 1e-5f);
    ab[c] = a;
    ab[C + c] = fmaf(-mean, a, bt[c]);
}

// ==== pooled raw bf16 -> BN+ReLU -> xcat bf16 [b][n][512] ====
__global__ void pool_convert(const bf16_t* __restrict__ pr, const float* __restrict__ ab,
                             bf16_t* __restrict__ xc, int C, int chofs, int logC) {
    int t = blockIdx.x * 256 + threadIdx.x;
    int c = t & (C - 1);
    int rest = t >> logC;
    int n = rest & (NP - 1);
    int b = rest >> 11;
    size_t p = ((size_t)b * NP + n) * 512 + chofs + c;
    float v = bf2f(pr[p]);
    xc[p] = f2bf(fmaxf(fmaf(ab[c], v, ab[C + c]), 0.f));
}

// ==== out: LDS-transpose tile (R13). Block = 32 n x 512 c (64 KB LDS). ====
__global__ __launch_bounds__(256) void out_kernel(const bf16_t* __restrict__ y5,
                                                  const float* __restrict__ ab,
                                                  float* __restrict__ out) {
    __shared__ float lds[32][512];
    const int t  = threadIdx.x;
    const int nb = blockIdx.x * 32;
    const int b  = blockIdx.y;
#pragma unroll
    for (int k = 0; k < 8; ++k) {
        int ch  = t + k * 256;        // 0..2047
        int row = ch >> 6;            // 0..31
        int c8  = (ch & 63) * 8;      // 0..504
        const bf16_t* yp = y5 + ((size_t)b * NP + nb + row) * 512 + c8;
        ushort4 u0 = *(const ushort4*)(yp);
        ushort4 u1 = *(const ushort4*)(yp + 4);
        float4 a0 = *(const float4*)(ab + c8);
        float4 a1 = *(const float4*)(ab + c8 + 4);
        float4 d0 = *(const float4*)(ab + 512 + c8);
        float4 d1 = *(const float4*)(ab + 512 + c8 + 4);
        lds[row][c8 + 0] = fmaxf(fmaf(a0.x, bf2f(u0.x), d0.x), 0.f);
        lds[row][c8 + 1] = fmaxf(fmaf(a0.y, bf2f(u0.y), d0.y), 0.f);
        lds[row][c8 + 2] = fmaxf(fmaf(a0.z, bf2f(u0.z), d0.z), 0.f);
        lds[row][c8 + 3] = fmaxf(fmaf(a0.w, bf2f(u0.w), d0.w), 0.f);
        lds[row][c8 + 4] = fmaxf(fmaf(a1.x, bf2f(u1.x), d1.x), 0.f);
        lds[row][c8 + 5] = fmaxf(fmaf(a1.y, bf2f(u1.y), d1.y), 0.f);
        lds[row][c8 + 6] = fmaxf(fmaf(a1.z, bf2f(u1.z), d1.z), 0.f);
        lds[row][c8 + 7] = fmaxf(fmaf(a1.w, bf2f(u1.w), d1.w), 0.f);
    }
    __syncthreads();
    const int n4   = t & 7;           // float4 index along n (covers 32 n)
    const int crow = t >> 3;          // 0..31
#pragma unroll
    for (int cc = 0; cc < 16; ++cc) {
        int c = crow + cc * 32;
        float4 v;
        v.x = lds[n4 * 4 + 0][c];
        v.y = lds[n4 * 4 + 1][c];
        v.z = lds[n4 * 4 + 2][c];
        v.w = lds[n4 * 4 + 3][c];
        *(float4*)(out + ((size_t)b * 1024 + c) * NP + nb + n4 * 4) = v;
    }
}

// ==== zero-fill out channels 512..1023 (33.5 MB float4 stream) ====
__global__ void zout_kernel(float* __restrict__ out) {
    size_t idx4 = (size_t)blockIdx.x * 256 + threadIdx.x;
    size_t off  = idx4 * 4;                       // float offset in pad region
    size_t per_b = (size_t)512 * NP;
    size_t b = off / per_b;
    size_t r = off - b * per_b;
    float4 z = make_float4(0.f, 0.f, 0.f, 0.f);
    *(float4*)(out + (b * 1024 + 512) * NP + r) = z;
}

extern "C" void kernel_launch(void* const* d_in, const int* in_sizes, int n_in,
                              void* d_out, int out_size, void* d_ws, size_t ws_size,
                              hipStream_t stream) {
    (void)in_sizes; (void)n_in; (void)out_size; (void)ws_size;
    const float* x  = (const float*)d_in[0];
    const float* W1 = (const float*)d_in[1];
    const float* W2 = (const float*)d_in[2];
    const float* W3 = (const float*)d_in[3];
    const float* W4 = (const float*)d_in[4];
    const float* W5 = (const float*)d_in[5];
    const float* g1 = (const float*)d_in[6];  const float* b1 = (const float*)d_in[7];
    const float* g2 = (const float*)d_in[8];  const float* b2 = (const float*)d_in[9];
    const float* g3 = (const float*)d_in[10]; const float* b3 = (const float*)d_in[11];
    const float* g4 = (const float*)d_in[12]; const float* b4 = (const float*)d_in[13];
    const float* g5 = (const float*)d_in[14]; const float* b5 = (const float*)d_in[15];

    // workspace, lifetime-aliased (R9 arena):
    // A @0: y2 | y5(bf16)   B @41943040: y1 | y3   (f tensor DELETED in R17)
    char* ws = (char*)d_ws;
    bf16_t* y2   = (bf16_t*)(ws + 0);
    bf16_t* y5   = (bf16_t*)(ws + 0);
    bf16_t* y1   = (bf16_t*)(ws + 41943040);
    bf16_t* y3   = (bf16_t*)(ws + 41943040);
    bf16_t* poolraw = (bf16_t*)(ws + 125829120);
    bf16_t* xcat    = (bf16_t*)(ws + 142606336);
    bf16_t* Wball   = (bf16_t*)(ws + 159383552);
    bf16_t* W1b = Wball;            // 64x32
    bf16_t* W2b = Wball + 2048;     // 64x64
    bf16_t* W3b = Wball + 6144;     // 128x64
    bf16_t* W4b = Wball + 14336;    // 256x128
    bf16_t* W5b = Wball + 47104;    // 512x512
    float* stats = (float*)(ws + 160002048);
    float* ab    = (float*)(ws + 160010240);
    int*  idx    = (int*)  (ws + 160018432);

    float* st1 = stats;        float* st2 = stats + 128;  float* st3 = stats + 256;
    float* st4 = stats + 512;  float* st5 = stats + 1024;
    float* ab1 = ab;       float* ab2 = ab + 128;  float* ab3 = ab + 256;
    float* ab4 = ab + 512; float* ab5 = ab + 1024;
    const float invM14 = 1.f / (float)(BB * SS);
    const float invM5  = 1.f / (float)(BB * NP);

    zstats_kernel<<<8, 256, 0, stream>>>(stats);
    wconv_kernel<<<8,    256, 0, stream>>>(W1, W1b, 64, 6, 32);
    wconv_kernel<<<16,   256, 0, stream>>>(W2, W2b, 64, 64, 64);
    wconv_kernel<<<32,   256, 0, stream>>>(W3, W3b, 128, 64, 64);
    wconv_kernel<<<128,  256, 0, stream>>>(W4, W4b, 256, 128, 128);
    wconv_kernel<<<1024, 256, 0, stream>>>(W5, W5b, 512, 512, 512);

    knn_kernel<<<1024, 256, 0, stream>>>(x, idx);

    // zero-pad half of out early (independent of everything else)
    zout_kernel<<<8192, 256, 0, stream>>>((float*)d_out);

    // L1: 6(pad32) -> 64   (GATHER mode: B frags built from x + idx in-kernel)
    mconv<32, 64, SS, 5, 8, true, true, true, true><<<dim3(32, 1, BB), 320, 0, stream>>>(
        nullptr, W1b, y1, poolraw, 0, st1, x, idx);
    bn_finalize<<<1, 64, 0, stream>>>(st1, g1, b1, ab1, 64, invM14);
    pool_convert<<<4096, 256, 0, stream>>>(poolraw, ab1, xcat, 64, 0, 6);
    bnrelu_kernel<<<10240, 256, 0, stream>>>(y1, ab1, 64);

    // L2: 64 -> 64   (NS=8; 256 blocks)
    mconv<64, 64, SS, 5, 8, true, true, true, false><<<dim3(32, 1, BB), 320, 0, stream>>>(
        y1, W2b, y2, poolraw, 64, st2, nullptr, nullptr);
    bn_finalize<<<1, 64, 0, stream>>>(st2, g2, b2, ab2, 64, invM14);
    pool_convert<<<4096, 256, 0, stream>>>(poolraw, ab2, xcat, 64, 64, 6);
    bnrelu_kernel<<<10240, 256, 0, stream>>>(y2, ab2, 64);

    // L3: 64 -> 128  (NS=16: 256 blocks = 1/CU)
    mconv<64, 128, SS, 5, 16, true, true, true, false><<<dim3(16, 2, BB), 320, 0, stream>>>(
        y2, W3b, y3, poolraw, 128, st3, nullptr, nullptr);
    bn_finalize<<<2, 64, 0, stream>>>(st3, g3, b3, ab3, 128, invM14);
    pool_convert<<<8192, 256, 0, stream>>>(poolraw, ab3, xcat, 128, 128, 7);
    bnrelu_kernel<<<20480, 256, 0, stream>>>(y3, ab3, 128);

    // L4: 128 -> 256, pool-only (NS=32: 256 blocks = 1/CU)
    mconv<128, 256, SS, 5, 32, true, false, true, false><<<dim3(8, 4, BB), 320, 0, stream>>>(
        y3, W4b, nullptr, poolraw, 256, st4, nullptr, nullptr);
    bn_finalize<<<4, 64, 0, stream>>>(st4, g4, b4, ab4, 256, invM14);
    pool_convert<<<16384, 256, 0, stream>>>(poolraw, ab4, xcat, 256, 256, 8);

    // L5: 512 -> 512 over [b][2048][512] (xcat already post-BN)
    mconv<512, 512, NP, 4, 1, false, true, false, false><<<dim3(16, 8, BB), 256, 0, stream>>>(
        xcat, W5b, y5, nullptr, 0, st5, nullptr, nullptr);
    bn_finalize<<<8, 64, 0, stream>>>(st5, g5, b5, ab5, 512, invM5);

    out_kernel<<<dim3(64, BB), 256, 0, stream>>>(y5, ab5, (float*)d_out);
}

// Round 18
// 399.588 us; speedup vs baseline: 1.0946x; 1.0338x over previous
//
#include <hip/hip_runtime.h>

#define BB  8
#define NP  2048
#define KNB 20
#define KP  10      // reduced ripple depth (validity-checked, exact fallback)
#define SS  40960   // spatial per batch, layers 1-4

typedef unsigned short bf16_t;
typedef __attribute__((ext_vector_type(8))) short short8_t;   // MFMA A/B frag (8 bf16)
typedef __attribute__((ext_vector_type(4))) float f32x4;      // MFMA C/D frag

static __device__ __forceinline__ float bf2f(unsigned short u) {
    return __uint_as_float(((unsigned)u) << 16);
}
static __device__ __forceinline__ bf16_t f2bf(float f) {
    unsigned u = __float_as_uint(f);
    return (bf16_t)((u + 0x7fffu + ((u >> 16) & 1u)) >> 16);   // RNE
}

#if __has_builtin(__builtin_amdgcn_fmed3f)
#define MED3(a, b, c) __builtin_amdgcn_fmed3f((a), (b), (c))
#else
#define MED3(a, b, c) fmaxf(fminf((a), (b)), fminf(fmaxf((a), (b)), (c)))
#endif

// ==== kNN v4 (KP=10, R9-verified) ====
static __device__ __forceinline__ float negdist(float4 me, float4 p) {
    float d = me.x * p.x + me.y * p.y + me.z * p.z;
    return 2.0f * d - me.w - p.w;
}

#define BDECL(t) float bv##t = -3.4e38f;
#define MCH(t, p) bv##t = MED3(v, bv##p, bv##t);
#define BSHIFT(t, n) bv##t = bv##n;
#define FDECL(t) float fv##t = -3.4e38f;
#define FMCH(t, p) fv##t = MED3(v, fv##p, fv##t);
#define FSHIFT(t, n) fv##t = fv##n;

__global__ __launch_bounds__(256) void knn_kernel(const float* __restrict__ x,
                                                  int* __restrict__ idx) {
    __shared__ float4 tile[2064];      // 2048 + (j>>7) swizzle pad, 33 KB
    __shared__ int   cnt[16];
    __shared__ float svv[16][44];
    __shared__ int   svj[16][44];
    const int tid  = threadIdx.x;
    const int b    = blockIdx.x >> 7;
    const int pblk = blockIdx.x & 127;
    const int pl   = tid >> 4;         // local point 0..15
    const int seg  = tid & 15;         // segment 0..15 (128 cands each)
    const int i    = pblk * 16 + pl;
    const float* xb = x + (size_t)b * 3 * NP;

    for (int j = tid; j < NP; j += 256) {
        float a0 = xb[j], a1 = xb[NP + j], a2 = xb[2 * NP + j];
        tile[j + (j >> 7)] = make_float4(a0, a1, a2, a0 * a0 + a1 * a1 + a2 * a2);
    }
    if (tid < 16) cnt[tid] = 0;
    __syncthreads();
    const float4 me = tile[i + (i >> 7)];
    const float4* tseg = &tile[seg * 129];

    // ---- phase 1: per-lane top-KP VALUES, depth-10 med3 ripple ----
    BDECL(0) BDECL(1) BDECL(2) BDECL(3) BDECL(4)
    BDECL(5) BDECL(6) BDECL(7) BDECL(8) BDECL(9)
    for (int t = 0; t < 128; ++t) {
        float v = negdist(me, tseg[t]);
        MCH(9,8) MCH(8,7) MCH(7,6) MCH(6,5) MCH(5,4)
        MCH(4,3) MCH(3,2) MCH(2,1) MCH(1,0)
        bv0 = fmaxf(bv0, v);
    }

    // ---- theta: 20 rounds of 16-lane argmax-with-pop (values only) ----
    float theta = -3.4e38f;
    int pops = 0;
    for (int r = 0; r < KNB; ++r) {
        float mv = bv0; int ms = seg;
#pragma unroll
        for (int s = 1; s <= 8; s <<= 1) {
            float ov = __shfl_xor(mv, s, 64);
            int   os = __shfl_xor(ms, s, 64);
            if (ov > mv || (ov == mv && os < ms)) { mv = ov; ms = os; }
        }
        if (seg == ms) {   // exactly one lane of the 16-group pops its head
            BSHIFT(0,1) BSHIFT(1,2) BSHIFT(2,3) BSHIFT(3,4) BSHIFT(4,5)
            BSHIFT(5,6) BSHIFT(6,7) BSHIFT(7,8) BSHIFT(8,9)
            bv9 = -3.4e38f;
            ++pops;
        }
        theta = mv;        // after round 19: the 20th-largest value
    }

    // ---- validity: a fully-drained lane may have corrupted later pops ----
    int bad = (pops >= KP) ? 1 : 0;
#pragma unroll
    for (int s = 1; s <= 8; s <<= 1) bad |= __shfl_xor(bad, s, 64);
    if (bad) {             // rare (~3e-6/point): exact full-depth redo
        FDECL(0)  FDECL(1)  FDECL(2)  FDECL(3)  FDECL(4)
        FDECL(5)  FDECL(6)  FDECL(7)  FDECL(8)  FDECL(9)
        FDECL(10) FDECL(11) FDECL(12) FDECL(13) FDECL(14)
        FDECL(15) FDECL(16) FDECL(17) FDECL(18) FDECL(19)
        for (int t = 0; t < 128; ++t) {
            float v = negdist(me, tseg[t]);
            FMCH(19,18) FMCH(18,17) FMCH(17,16) FMCH(16,15) FMCH(15,14)
            FMCH(14,13) FMCH(13,12) FMCH(12,11) FMCH(11,10) FMCH(10,9)
            FMCH(9,8)   FMCH(8,7)   FMCH(7,6)   FMCH(6,5)   FMCH(5,4)
            FMCH(4,3)   FMCH(3,2)   FMCH(2,1)   FMCH(1,0)
            fv0 = fmaxf(fv0, v);
        }
        theta = -3.4e38f;
        for (int r = 0; r < KNB; ++r) {
            float mv = fv0; int ms = seg;
#pragma unroll
            for (int s = 1; s <= 8; s <<= 1) {
                float ov = __shfl_xor(mv, s, 64);
                int   os = __shfl_xor(ms, s, 64);
                if (ov > mv || (ov == mv && os < ms)) { mv = ov; ms = os; }
            }
            if (seg == ms) {
                FSHIFT(0,1)   FSHIFT(1,2)   FSHIFT(2,3)   FSHIFT(3,4)   FSHIFT(4,5)
                FSHIFT(5,6)   FSHIFT(6,7)   FSHIFT(7,8)   FSHIFT(8,9)   FSHIFT(9,10)
                FSHIFT(10,11) FSHIFT(11,12) FSHIFT(12,13) FSHIFT(13,14) FSHIFT(14,15)
                FSHIFT(15,16) FSHIFT(16,17) FSHIFT(17,18) FSHIFT(18,19)
                fv19 = -3.4e38f;
            }
            theta = mv;
        }
    }

    // ---- phase 2: collect survivors (v >= theta), identical arithmetic ----
    for (int t = 0; t < 128; ++t) {
        float v = negdist(me, tseg[t]);
        if (v >= theta) {
            int k = atomicAdd(&cnt[pl], 1);
            if (k < 44) { svv[pl][k] = v; svj[pl][k] = seg * 128 + t; }
        }
    }
    __syncthreads();

    // ---- emit: rank = #{(v',j') : v'>v or (v'==v && j'<j)} ----
    int n = cnt[pl]; if (n > 44) n = 44;
    int* o = idx + ((size_t)b * NP + i) * KNB;
    for (int e = seg; e < n; e += 16) {
        float v = svv[pl][e]; int j = svj[pl][e];
        int rank = 0;
        for (int q = 0; q < n; ++q) {
            float vq = svv[pl][q]; int jq = svj[pl][q];
            rank += (vq > v || (vq == v && jq < j)) ? 1 : 0;
        }
        if (rank < KNB) o[rank] = j;
    }
}

// ==== weights fp32 -> bf16, zero-padded rows ====
__global__ void wconv_kernel(const float* __restrict__ src, bf16_t* __restrict__ dst,
                             int O, int CI, int CIP) {
    int t = blockIdx.x * 256 + threadIdx.x;
    if (t >= O * CIP) return;
    int o = t / CIP, cp = t - o * CIP;
    dst[t] = (cp < CI) ? f2bf(src[o * CI + cp]) : (bf16_t)0;
}

// ==== zero the layer-stats accumulators (2048 floats) ====
__global__ void zstats_kernel(float* __restrict__ p) {
    p[blockIdx.x * 256 + threadIdx.x] = 0.f;
}

// ==== R18 fused per-layer post-pass: bn_finalize + pool_convert + bnrelu
// in ONE kernel. Every block first computes the BN affine coefs from
// stats/g/bt into LDS (<=C threads, ~10 VALU each, amortized over the
// block's streaming work — NOT per-element, avoiding the R11 VALU trap),
// then branches by blockIdx.x into the pool_convert stream or the bnrelu
// stream. Bit-identical math to the three deleted kernels.
template<int C, int LOGC, bool BNR>
__global__ __launch_bounds__(256)
void post_kernel(const float* __restrict__ stats, const float* __restrict__ g,
                 const float* __restrict__ bt, float invM,
                 const bf16_t* __restrict__ pr, bf16_t* __restrict__ xc, int chofs,
                 bf16_t* __restrict__ y, int pblocks) {
    __shared__ float abL[2 * C];
    const int t = threadIdx.x;
    for (int c = t; c < C; c += 256) {
        float mean = stats[c] * invM;
        float var  = fmaxf(stats[C + c] * invM - mean * mean, 0.f);
        float a = g[c] * rsqrtf(var + 1e-5f);
        abL[c] = a;
        abL[C + c] = fmaf(-mean, a, bt[c]);
    }
    __syncthreads();

    if ((int)blockIdx.x < pblocks) {
        // pool_convert: pooled raw bf16 -> BN+ReLU -> xcat [b][n][512]
        int tt = blockIdx.x * 256 + t;
        int c = tt & (C - 1);
        int rest = tt >> LOGC;
        int n = rest & (NP - 1);
        int b = rest >> 11;
        size_t p = ((size_t)b * NP + n) * 512 + chofs + c;
        float v = bf2f(pr[p]);
        xc[p] = f2bf(fmaxf(fmaf(abL[c], v, abL[C + c]), 0.f));
    } else if constexpr (BNR) {
        // bnrelu in place on y [.., C contiguous], 8 elems/thread
        size_t e0 = ((size_t)(blockIdx.x - pblocks) * 256 + t) * 8;
        int c0 = (int)(e0 & (size_t)(C - 1));
        uint4 r = *(uint4*)(y + e0);
        float4 a0 = *(const float4*)(&abL[c0]);
        float4 a1 = *(const float4*)(&abL[c0 + 4]);
        float4 d0 = *(const float4*)(&abL[C + c0]);
        float4 d1 = *(const float4*)(&abL[C + c0 + 4]);
        float v0 = bf2f((unsigned short)(r.x & 0xffffu)), v1 = bf2f((unsigned short)(r.x >> 16));
        float v2 = bf2f((unsigned short)(r.y & 0xffffu)), v3 = bf2f((unsigned short)(r.y >> 16));
        float v4 = bf2f((unsigned short)(r.z & 0xffffu)), v5 = bf2f((unsigned short)(r.z >> 16));
        float v6 = bf2f((unsigned short)(r.w & 0xffffu)), v7 = bf2f((unsigned short)(r.w >> 16));
        v0 = fmaxf(fmaf(a0.x, v0, d0.x), 0.f); v1 = fmaxf(fmaf(a0.y, v1, d0.y), 0.f);
        v2 = fmaxf(fmaf(a0.z, v2, d0.z), 0.f); v3 = fmaxf(fmaf(a0.w, v3, d0.w), 0.f);
        v4 = fmaxf(fmaf(a1.x, v4, d1.x), 0.f); v5 = fmaxf(fmaf(a1.y, v5, d1.y), 0.f);
        v6 = fmaxf(fmaf(a1.z, v6, d1.z), 0.f); v7 = fmaxf(fmaf(a1.w, v7, d1.w), 0.f);
        r.x = (unsigned)f2bf(v0) | ((unsigned)f2bf(v1) << 16);
        r.y = (unsigned)f2bf(v2) | ((unsigned)f2bf(v3) << 16);
        r.z = (unsigned)f2bf(v4) | ((unsigned)f2bf(v5) << 16);
        r.w = (unsigned)f2bf(v6) | ((unsigned)f2bf(v7) << 16);
        *(uint4*)(y + e0) = r;
    }
}

// ==== MFMA conv: unchanged from R17 (reg B-prefetch, ping-pong ytile,
// lgkm-only barrier, rolled NS loop, max-NS grids, GATHER mode for L1,
// L5 K-loop dbuf) ====
#define MF(A, B, C) C = __builtin_amdgcn_mfma_f32_16x16x32_bf16(A, B, C, 0, 0, 0);

#define LGKM_BARRIER() { \
    asm volatile("s_waitcnt lgkmcnt(0)" ::: "memory"); \
    __builtin_amdgcn_s_barrier(); \
    asm volatile("" ::: "memory"); }

#define TILE1(CC, CT, STt, YT) { \
    ushort4 t4; \
    t4.x = f2bf(CC[0]); t4.y = f2bf(CC[1]); \
    t4.z = f2bf(CC[2]); t4.w = f2bf(CC[3]); \
    *(ushort4*)&YT[w * 32 + (STt) * 16 + col][(CT) * 16 + quad * 4] = t4; }

// build L1 B fragment for row r (only quad 0 nonzero; matches old gather)
static __device__ __forceinline__ short8_t gfrag(const float* __restrict__ xb,
                                                 const int* __restrict__ idxb,
                                                 int r, int q8) {
    short8_t f = {0, 0, 0, 0, 0, 0, 0, 0};
    if (q8 == 0) {
        int n = r / KNB;
        int j = idxb[r];
        f[0] = (short)f2bf(xb[j]);
        f[1] = (short)f2bf(xb[NP + j]);
        f[2] = (short)f2bf(xb[2 * NP + j]);
        f[3] = (short)f2bf(xb[n]);
        f[4] = (short)f2bf(xb[NP + n]);
        f[5] = (short)f2bf(xb[2 * NP + n]);
    }
    return f;
}

// shared epilogue body; expects c00..c31 in scope. ONE lgkm-barrier.
#define EPILOGUE(ITV) { \
    bf16_t (*yt)[68] = ytile[(ITV) & (NBUF - 1)]; \
    TILE1(c00,0,0,yt) TILE1(c10,1,0,yt) TILE1(c20,2,0,yt) TILE1(c30,3,0,yt) \
    TILE1(c01,0,1,yt) TILE1(c11,1,1,yt) TILE1(c21,2,1,yt) TILE1(c31,3,1,yt) \
    LGKM_BARRIER() \
    if constexpr (ST) { \
        const int row0 = blockIdx.x * (SR * NS) + (ITV) * SR; \
        for (int i = tid; i < SR * 16; i += NW * 64) { \
            int row = i >> 4, c4 = (i & 15) * 4; \
            ushort4 yv = *(const ushort4*)&yt[row][c4]; \
            *(ushort4*)(Yout + ((size_t)b * SROWS + row0 + row) * COUT_T + cob + c4) = yv; \
            if constexpr (!POOL) { \
                float v0 = bf2f(yv.x), v1 = bf2f(yv.y); \
                float v2 = bf2f(yv.z), v3 = bf2f(yv.w); \
                sv0 += v0; qv0 = fmaf(v0, v0, qv0); \
                sv1 += v1; qv1 = fmaf(v1, v1, qv1); \
                sv2 += v2; qv2 = fmaf(v2, v2, qv2); \
                sv3 += v3; qv3 = fmaf(v3, v3, qv3); \
            } \
        } \
    } \
    if constexpr (POOL) { \
        const int nbase = (blockIdx.x * NS + (ITV)) * 8; \
        for (int i = tid; i < 8 * 32; i += NW * 64) { \
            const int nl = i >> 5, c2 = (i & 31) * 2; \
            float m0 = -3.4e38f, m1 = -3.4e38f; \
            _Pragma("unroll") \
            for (int k = 0; k < KNB; ++k) { \
                unsigned u = *(const unsigned*)&yt[nl * 20 + k][c2]; \
                float v0 = bf2f((unsigned short)(u & 0xffffu)); \
                float v1 = bf2f((unsigned short)(u >> 16)); \
                m0 = fmaxf(m0, v0); m1 = fmaxf(m1, v1); \
                svA += v0; qvA = fmaf(v0, v0, qvA); \
                svB += v1; qvB = fmaf(v1, v1, qvB); \
            } \
            unsigned r2 = (unsigned)f2bf(m0) | ((unsigned)f2bf(m1) << 16); \
            *(unsigned*)(poolOut + ((size_t)b * NP + nbase + nl) * 512 + chofs + cob + c2) = r2; \
        } \
    } \
}

template<int CIN, int COUT_T, int SROWS, int NW, int NS, bool POOL, bool ST, bool PRE, bool GATHER>
__global__ __launch_bounds__(320)
void mconv(const bf16_t* __restrict__ H, const bf16_t* __restrict__ Wb,
           bf16_t* __restrict__ Yout, bf16_t* __restrict__ poolOut,
           int chofs, float* __restrict__ stats,
           const float* __restrict__ Xg, const int* __restrict__ IdxG) {
    constexpr int SR = NW * 32;
    constexpr int NKK = CIN / 32;
    constexpr int NBUF = (NS > 1) ? 2 : 1;
    __shared__ bf16_t ytile[NBUF][SR][68];
    __shared__ float redS[NW][64];
    __shared__ float redQ[NW][64];
    const int tid  = threadIdx.x;
    const int lane = tid & 63, col = lane & 15, quad = lane >> 4, q8 = quad * 8;
    const int w    = tid >> 6;
    const int cob  = blockIdx.y * 64;
    const int b    = blockIdx.z;
    const bf16_t* wp = Wb + (size_t)(cob + col) * CIN + q8;
    const float* xb = GATHER ? (Xg + (size_t)b * 3 * NP) : nullptr;
    const int* idxb = GATHER ? (IdxG + (size_t)b * SS) : nullptr;

    // per-thread BN-stat accumulators (channel fixed per thread; see loops)
    float svA = 0.f, svB = 0.f, qvA = 0.f, qvB = 0.f;              // POOL path
    float sv0 = 0.f, sv1 = 0.f, sv2 = 0.f, sv3 = 0.f;              // ST (L5) path
    float qv0 = 0.f, qv1 = 0.f, qv2 = 0.f, qv3 = 0.f;

    if constexpr (PRE) {
        // A fragments, statically-indexed arrays (loop-invariant weights)
        short8_t Af0[NKK], Af1[NKK], Af2[NKK], Af3[NKK];
#pragma unroll
        for (int kk = 0; kk < NKK; ++kk) {
            Af0[kk] = *(const short8_t*)(wp + kk * 32);
            Af1[kk] = *(const short8_t*)(wp + 16 * CIN + kk * 32);
            Af2[kk] = *(const short8_t*)(wp + 32 * CIN + kk * 32);
            Af3[kk] = *(const short8_t*)(wp + 48 * CIN + kk * 32);
        }

        // B-fragment double buffer: cur + next
        short8_t cb0[NKK], cb1[NKK], nb0[NKK], nb1[NKK];
        {
            const int sb = blockIdx.x * (SR * NS) + w * 32;
            if constexpr (GATHER) {
                cb0[0] = gfrag(xb, idxb, sb + col, q8);
                cb1[0] = gfrag(xb, idxb, sb + col + 16, q8);
            } else {
                const bf16_t* hp0 = H + ((size_t)b * SROWS + sb + col) * CIN + q8;
                const bf16_t* hp1 = hp0 + 16 * CIN;
#pragma unroll
                for (int kk = 0; kk < NKK; ++kk) {
                    cb0[kk] = *(const short8_t*)(hp0 + kk * 32);
                    cb1[kk] = *(const short8_t*)(hp1 + kk * 32);
                }
            }
        }

#pragma unroll 1
        for (int it = 0; it < NS; ++it) {
            // prefetch next tile's B frags; with the lgkm-only barrier these
            // stay in flight across it and land under the pool epilogue
            if (it + 1 < NS) {
                const int sb = blockIdx.x * (SR * NS) + (it + 1) * SR + w * 32;
                if constexpr (GATHER) {
                    nb0[0] = gfrag(xb, idxb, sb + col, q8);
                    nb1[0] = gfrag(xb, idxb, sb + col + 16, q8);
                } else {
                    const bf16_t* hp0 = H + ((size_t)b * SROWS + sb + col) * CIN + q8;
                    const bf16_t* hp1 = hp0 + 16 * CIN;
#pragma unroll
                    for (int kk = 0; kk < NKK; ++kk) {
                        nb0[kk] = *(const short8_t*)(hp0 + kk * 32);
                        nb1[kk] = *(const short8_t*)(hp1 + kk * 32);
                    }
                }
            }

            f32x4 c00 = {0.f,0.f,0.f,0.f}, c10 = c00, c20 = c00, c30 = c00;
            f32x4 c01 = c00, c11 = c00, c21 = c00, c31 = c00;
#pragma unroll
            for (int kk = 0; kk < NKK; ++kk) {
                MF(Af0[kk], cb0[kk], c00) MF(Af1[kk], cb0[kk], c10)
                MF(Af2[kk], cb0[kk], c20) MF(Af3[kk], cb0[kk], c30)
                MF(Af0[kk], cb1[kk], c01) MF(Af1[kk], cb1[kk], c11)
                MF(Af2[kk], cb1[kk], c21) MF(Af3[kk], cb1[kk], c31)
            }

            EPILOGUE(it)

            if (it + 1 < NS) {
#pragma unroll
                for (int kk = 0; kk < NKK; ++kk) { cb0[kk] = nb0[kk]; cb1[kk] = nb1[kk]; }
            }
        }
    } else {
        // L5: K-loop register double-buffer (prefetch k0+32 while MFMA on k0)
        for (int it = 0; it < NS; ++it) {
            const int sb = blockIdx.x * (SR * NS) + it * SR + w * 32;
            const bf16_t* hp0 = H + ((size_t)b * SROWS + sb + col) * CIN + q8;
            const bf16_t* hp1 = hp0 + 16 * CIN;

            f32x4 c00 = {0.f,0.f,0.f,0.f}, c10 = c00, c20 = c00, c30 = c00;
            f32x4 c01 = c00, c11 = c00, c21 = c00, c31 = c00;

            short8_t a0c = *(const short8_t*)(wp);
            short8_t a1c = *(const short8_t*)(wp + 16 * CIN);
            short8_t a2c = *(const short8_t*)(wp + 32 * CIN);
            short8_t a3c = *(const short8_t*)(wp + 48 * CIN);
            short8_t b0c = *(const short8_t*)(hp0);
            short8_t b1c = *(const short8_t*)(hp1);

#pragma unroll 1
            for (int k0 = 0; k0 < CIN; k0 += 32) {
                short8_t a0n, a1n, a2n, a3n, b0n, b1n;
                if (k0 + 32 < CIN) {
                    a0n = *(const short8_t*)(wp + k0 + 32);
                    a1n = *(const short8_t*)(wp + 16 * CIN + k0 + 32);
                    a2n = *(const short8_t*)(wp + 32 * CIN + k0 + 32);
                    a3n = *(const short8_t*)(wp + 48 * CIN + k0 + 32);
                    b0n = *(const short8_t*)(hp0 + k0 + 32);
                    b1n = *(const short8_t*)(hp1 + k0 + 32);
                }
                MF(a0c, b0c, c00) MF(a1c, b0c, c10) MF(a2c, b0c, c20) MF(a3c, b0c, c30)
                MF(a0c, b1c, c01) MF(a1c, b1c, c11) MF(a2c, b1c, c21) MF(a3c, b1c, c31)
                if (k0 + 32 < CIN) {
                    a0c = a0n; a1c = a1n; a2c = a2n; a3c = a3n;
                    b0c = b0n; b1c = b1n;
                }
            }

            EPILOGUE(it)
        }
    }

    // ---- BN-stat wave reduction -> redS/redQ -> global atomics ----
    if constexpr (POOL) {
        // thread's channel pair: c2=(lane&31)*2; halves of the wave (nl parity)
        // combine via one xor-32 shuffle
        svA += __shfl_xor(svA, 32, 64); qvA += __shfl_xor(qvA, 32, 64);
        svB += __shfl_xor(svB, 32, 64); qvB += __shfl_xor(qvB, 32, 64);
        if (lane < 32) {
            const int c2 = lane * 2;
            redS[w][c2] = svA; redS[w][c2 + 1] = svB;
            redQ[w][c2] = qvA; redQ[w][c2 + 1] = qvB;
        }
    } else if constexpr (ST) {
        // thread's channel quad: c4=(lane&15)*4; lanes differing in bits 4,5 share it
        sv0 += __shfl_xor(sv0, 16, 64); qv0 += __shfl_xor(qv0, 16, 64);
        sv1 += __shfl_xor(sv1, 16, 64); qv1 += __shfl_xor(qv1, 16, 64);
        sv2 += __shfl_xor(sv2, 16, 64); qv2 += __shfl_xor(qv2, 16, 64);
        sv3 += __shfl_xor(sv3, 16, 64); qv3 += __shfl_xor(qv3, 16, 64);
        sv0 += __shfl_xor(sv0, 32, 64); qv0 += __shfl_xor(qv0, 32, 64);
        sv1 += __shfl_xor(sv1, 32, 64); qv1 += __shfl_xor(qv1, 32, 64);
        sv2 += __shfl_xor(sv2, 32, 64); qv2 += __shfl_xor(qv2, 32, 64);
        sv3 += __shfl_xor(sv3, 32, 64); qv3 += __shfl_xor(qv3, 32, 64);
        if (lane < 16) {
            const int c4 = lane * 4;
            redS[w][c4]     = sv0; redS[w][c4 + 1] = sv1;
            redS[w][c4 + 2] = sv2; redS[w][c4 + 3] = sv3;
            redQ[w][c4]     = qv0; redQ[w][c4 + 1] = qv1;
            redQ[w][c4 + 2] = qv2; redQ[w][c4 + 3] = qv3;
        }
    }
    __syncthreads();
    if (tid < 64) {
        float sv = 0.f, qv = 0.f;
#pragma unroll
        for (int ch = 0; ch < NW; ++ch) { sv += redS[ch][tid]; qv += redQ[ch][tid]; }
        atomicAdd(&stats[cob + tid], sv);
        atomicAdd(&stats[COUT_T + cob + tid], qv);
    }
}

// ==== out: LDS-transpose tile + in-kernel bn_finalize for L5 (R18).
// Block = 32 n x 512 c (64 KB LDS) + abL[1024] (4 KB). ====
__global__ __launch_bounds__(256) void out_kernel(const bf16_t* __restrict__ y5,
                                                  const float* __restrict__ stats,
                                                  const float* __restrict__ g,
                                                  const float* __restrict__ bt,
                                                  float invM,
                                                  float* __restrict__ out) {
    __shared__ float lds[32][512];
    __shared__ float abL[1024];
    const int t  = threadIdx.x;
    const int nb = blockIdx.x * 32;
    const int b  = blockIdx.y;
#pragma unroll
    for (int cc = 0; cc < 2; ++cc) {
        int c = t + cc * 256;
        float mean = stats[c] * invM;
        float var  = fmaxf(stats[512 + c] * invM - mean * mean, 0.f);
        float a = g[c] * rsqrtf(var + 1e-5f);
        abL[c] = a;
        abL[512 + c] = fmaf(-mean, a, bt[c]);
    }
    __syncthreads();
#pragma unroll
    for (int k = 0; k < 8; ++k) {
        int ch  = t + k * 256;        // 0..2047
        int row = ch >> 6;            // 0..31
        int c8  = (ch & 63) * 8;      // 0..504
        const bf16_t* yp = y5 + ((size_t)b * NP + nb + row) * 512 + c8;
        ushort4 u0 = *(const ushort4*)(yp);
        ushort4 u1 = *(const ushort4*)(yp + 4);
        float4 a0 = *(const float4*)(&abL[c8]);
        float4 a1 = *(const float4*)(&abL[c8 + 4]);
        float4 d0 = *(const float4*)(&abL[512 + c8]);
        float4 d1 = *(const float4*)(&abL[512 + c8 + 4]);
        lds[row][c8 + 0] = fmaxf(fmaf(a0.x, bf2f(u0.x), d0.x), 0.f);
        lds[row][c8 + 1] = fmaxf(fmaf(a0.y, bf2f(u0.y), d0.y), 0.f);
        lds[row][c8 + 2] = fmaxf(fmaf(a0.z, bf2f(u0.z), d0.z), 0.f);
        lds[row][c8 + 3] = fmaxf(fmaf(a0.w, bf2f(u0.w), d0.w), 0.f);
        lds[row][c8 + 4] = fmaxf(fmaf(a1.x, bf2f(u1.x), d1.x), 0.f);
        lds[row][c8 + 5] = fmaxf(fmaf(a1.y, bf2f(u1.y), d1.y), 0.f);
        lds[row][c8 + 6] = fmaxf(fmaf(a1.z, bf2f(u1.z), d1.z), 0.f);
        lds[row][c8 + 7] = fmaxf(fmaf(a1.w, bf2f(u1.w), d1.w), 0.f);
    }
    __syncthreads();
    const int n4   = t & 7;           // float4 index along n (covers 32 n)
    const int crow = t >> 3;          // 0..31
#pragma unroll
    for (int cc = 0; cc < 16; ++cc) {
        int c = crow + cc * 32;
        float4 v;
        v.x = lds[n4 * 4 + 0][c];
        v.y = lds[n4 * 4 + 1][c];
        v.z = lds[n4 * 4 + 2][c];
        v.w = lds[n4 * 4 + 3][c];
        *(float4*)(out + ((size_t)b * 1024 + c) * NP + nb + n4 * 4) = v;
    }
}

// ==== zero-fill out channels 512..1023 (33.5 MB float4 stream) ====
__global__ void zout_kernel(float* __restrict__ out) {
    size_t idx4 = (size_t)blockIdx.x * 256 + threadIdx.x;
    size_t off  = idx4 * 4;                       // float offset in pad region
    size_t per_b = (size_t)512 * NP;
    size_t b = off / per_b;
    size_t r = off - b * per_b;
    float4 z = make_float4(0.f, 0.f, 0.f, 0.f);
    *(float4*)(out + (b * 1024 + 512) * NP + r) = z;
}

extern "C" void kernel_launch(void* const* d_in, const int* in_sizes, int n_in,
                              void* d_out, int out_size, void* d_ws, size_t ws_size,
                              hipStream_t stream) {
    (void)in_sizes; (void)n_in; (void)out_size; (void)ws_size;
    const float* x  = (const float*)d_in[0];
    const float* W1 = (const float*)d_in[1];
    const float* W2 = (const float*)d_in[2];
    const float* W3 = (const float*)d_in[3];
    const float* W4 = (const float*)d_in[4];
    const float* W5 = (const float*)d_in[5];
    const float* g1 = (const float*)d_in[6];  const float* b1 = (const float*)d_in[7];
    const float* g2 = (const float*)d_in[8];  const float* b2 = (const float*)d_in[9];
    const float* g3 = (const float*)d_in[10]; const float* b3 = (const float*)d_in[11];
    const float* g4 = (const float*)d_in[12]; const float* b4 = (const float*)d_in[13];
    const float* g5 = (const float*)d_in[14]; const float* b5 = (const float*)d_in[15];

    // workspace, lifetime-aliased (R9 arena):
    // A @0: y2 | y5(bf16)   B @41943040: y1 | y3   (f tensor deleted in R17)
    char* ws = (char*)d_ws;
    bf16_t* y2   = (bf16_t*)(ws + 0);
    bf16_t* y5   = (bf16_t*)(ws + 0);
    bf16_t* y1   = (bf16_t*)(ws + 41943040);
    bf16_t* y3   = (bf16_t*)(ws + 41943040);
    bf16_t* poolraw = (bf16_t*)(ws + 125829120);
    bf16_t* xcat    = (bf16_t*)(ws + 142606336);
    bf16_t* Wball   = (bf16_t*)(ws + 159383552);
    bf16_t* W1b = Wball;            // 64x32
    bf16_t* W2b = Wball + 2048;     // 64x64
    bf16_t* W3b = Wball + 6144;     // 128x64
    bf16_t* W4b = Wball + 14336;    // 256x128
    bf16_t* W5b = Wball + 47104;    // 512x512
    float* stats = (float*)(ws + 160002048);
    int*  idx    = (int*)  (ws + 160018432);

    float* st1 = stats;        float* st2 = stats + 128;  float* st3 = stats + 256;
    float* st4 = stats + 512;  float* st5 = stats + 1024;
    const float invM14 = 1.f / (float)(BB * SS);
    const float invM5  = 1.f / (float)(BB * NP);

    zstats_kernel<<<8, 256, 0, stream>>>(stats);
    wconv_kernel<<<8,    256, 0, stream>>>(W1, W1b, 64, 6, 32);
    wconv_kernel<<<16,   256, 0, stream>>>(W2, W2b, 64, 64, 64);
    wconv_kernel<<<32,   256, 0, stream>>>(W3, W3b, 128, 64, 64);
    wconv_kernel<<<128,  256, 0, stream>>>(W4, W4b, 256, 128, 128);
    wconv_kernel<<<1024, 256, 0, stream>>>(W5, W5b, 512, 512, 512);

    knn_kernel<<<1024, 256, 0, stream>>>(x, idx);

    // zero-pad half of out early (independent of everything else)
    zout_kernel<<<8192, 256, 0, stream>>>((float*)d_out);

    // L1: 6(pad32) -> 64   (GATHER mode: B frags built from x + idx in-kernel)
    mconv<32, 64, SS, 5, 8, true, true, true, true><<<dim3(32, 1, BB), 320, 0, stream>>>(
        nullptr, W1b, y1, poolraw, 0, st1, x, idx);
    post_kernel<64, 6, true><<<4096 + 10240, 256, 0, stream>>>(
        st1, g1, b1, invM14, poolraw, xcat, 0, y1, 4096);

    // L2: 64 -> 64   (NS=8; 256 blocks)
    mconv<64, 64, SS, 5, 8, true, true, true, false><<<dim3(32, 1, BB), 320, 0, stream>>>(
        y1, W2b, y2, poolraw, 64, st2, nullptr, nullptr);
    post_kernel<64, 6, true><<<4096 + 10240, 256, 0, stream>>>(
        st2, g2, b2, invM14, poolraw, xcat, 64, y2, 4096);

    // L3: 64 -> 128  (NS=16: 256 blocks = 1/CU)
    mconv<64, 128, SS, 5, 16, true, true, true, false><<<dim3(16, 2, BB), 320, 0, stream>>>(
        y2, W3b, y3, poolraw, 128, st3, nullptr, nullptr);
    post_kernel<128, 7, true><<<8192 + 20480, 256, 0, stream>>>(
        st3, g3, b3, invM14, poolraw, xcat, 128, y3, 8192);

    // L4: 128 -> 256, pool-only (NS=32: 256 blocks = 1/CU)
    mconv<128, 256, SS, 5, 32, true, false, true, false><<<dim3(8, 4, BB), 320, 0, stream>>>(
        y3, W4b, nullptr, poolraw, 256, st4, nullptr, nullptr);
    post_kernel<256, 8, false><<<16384, 256, 0, stream>>>(
        st4, g4, b4, invM14, poolraw, xcat, 256, nullptr, 16384);

    // L5: 512 -> 512 over [b][2048][512] (xcat already post-BN)
    mconv<512, 512, NP, 4, 1, false, true, false, false><<<dim3(16, 8, BB), 256, 0, stream>>>(
        xcat, W5b, y5, nullptr, 0, st5, nullptr, nullptr);

    // out: bn_finalize(st5) fused in-kernel
    out_kernel<<<dim3(64, BB), 256, 0, stream>>>(y5, st5, g5, b5, invM5, (float*)d_out);
}